// Round 2
// baseline (1023.251 us; speedup 1.0000x reference)
//
#include <hip/hip_runtime.h>
#include <hip/hip_bf16.h>

#define Bb  8
#define Cc  64
#define Tt  16
#define Vv  207
#define Hh  8
#define DH  8
#define NW  4
#define WSZ 4
#define Nn  (WSZ*Vv)       // 828
#define TV  (Tt*Vv)        // 3312
#define CTV (Cc*Tt*Vv)     // 211968
#define S   (Bb*CTV)       // 1695744
#define EPSF 1e-5f

__global__ void zero_stats_kernel(float* stats) {
    stats[threadIdx.x] = 0.f;   // 64 floats: 4 LN slots x (B*2)
}

// ---------------- QKV: per position, row [64] x W[64,192] ----------------
// grid = B*T*V blocks, 192 threads
__global__ void qkv_kernel(const float* __restrict__ xin,
                           const float* __restrict__ w,
                           const float* __restrict__ bias,
                           float* __restrict__ q, float* __restrict__ k, float* __restrict__ v) {
    __shared__ float xrow[Cc];
    int p = blockIdx.x;              // b*TV + t*V + v
    int b = p / TV; int r = p % TV; int t = r / Vv; int vv = r % Vv;
    int tid = threadIdx.x;           // 0..191
    if (tid < Cc) xrow[tid] = xin[((size_t)(b*Cc + tid)*Tt + t)*Vv + vv];
    __syncthreads();
    float acc = bias[tid];
    #pragma unroll 8
    for (int c = 0; c < Cc; ++c) acc += xrow[c] * w[c*192 + tid];
    int which = tid >> 6; int cc = tid & 63;
    int h = cc >> 3; int d = cc & 7;
    int w_ = t / WSZ; int tw = t % WSZ;
    int n = tw*Vv + vv;
    float* dst = (which == 0) ? q : ((which == 1) ? k : v);
    dst[((((size_t)(b*NW + w_))*Hh + h)*Nn + n)*DH + d] = acc;
}

// ---------------- Attention: one thread per query row, online softmax ----------------
// grid = B*NW*H*4 blocks (4 row-chunks of 256), 256 threads
__global__ __launch_bounds__(256) void attn_kernel(const float* __restrict__ q,
                                                   const float* __restrict__ k,
                                                   const float* __restrict__ v,
                                                   float* __restrict__ att) {
    __shared__ float ks[Nn*DH];
    __shared__ float vs[Nn*DH];
    int bwh = blockIdx.x >> 2;
    int chunk = blockIdx.x & 3;
    const float* kbase = k + (size_t)bwh*Nn*DH;
    const float* vbase = v + (size_t)bwh*Nn*DH;
    for (int i = threadIdx.x; i < Nn*DH; i += 256) { ks[i] = kbase[i]; vs[i] = vbase[i]; }
    __syncthreads();
    int n = chunk*256 + threadIdx.x;
    if (n >= Nn) return;
    const float* qrow = q + ((size_t)bwh*Nn + n)*DH;
    float qr[DH];
    #pragma unroll
    for (int d = 0; d < DH; ++d) qr[d] = qrow[d] * 0.35355339059327373f; // 1/sqrt(8)
    float mrun = -1e30f, l = 0.f;
    float acc[DH] = {0.f,0.f,0.f,0.f,0.f,0.f,0.f,0.f};
    for (int m = 0; m < Nn; ++m) {
        float s = 0.f;
        #pragma unroll
        for (int d = 0; d < DH; ++d) s += qr[d]*ks[m*DH+d];
        if (s > mrun) {
            float corr = __expf(mrun - s);
            l *= corr;
            #pragma unroll
            for (int d = 0; d < DH; ++d) acc[d] *= corr;
            mrun = s;
        }
        float p = __expf(s - mrun);
        l += p;
        #pragma unroll
        for (int d = 0; d < DH; ++d) acc[d] += p*vs[m*DH+d];
    }
    int h = bwh & 7; int bw = bwh >> 3;          // bw = b*NW + w
    float inv = 1.f / l;
    float* dst = att + ((size_t)bw*Nn + n)*Cc + h*DH;
    #pragma unroll
    for (int d = 0; d < DH; ++d) dst[d] = acc[d]*inv;
}

// ---------------- Proj + residual ----------------
// grid = B*T*V/4 blocks, 256 threads (4 positions x 64 channels)
__global__ void proj_kernel(const float* __restrict__ att,
                            const float* __restrict__ wo,
                            const float* __restrict__ bo,
                            const float* __restrict__ resid, float* __restrict__ out) {
    __shared__ float rows[4][Cc];
    int tid = threadIdx.x;
    int pl = tid >> 6; int c = tid & 63;
    int p = blockIdx.x*4 + pl;
    int b = p / TV; int r = p % TV; int t = r / Vv; int vv = r % Vv;
    int w_ = t / WSZ; int tw = t % WSZ; int n = tw*Vv + vv;
    const float* arow = att + ((size_t)(b*NW + w_)*Nn + n)*Cc;
    rows[pl][c] = arow[c];
    __syncthreads();
    float acc = bo[c];
    #pragma unroll 8
    for (int cc = 0; cc < Cc; ++cc) acc += rows[pl][cc] * wo[cc*Cc + c];
    size_t oi = ((size_t)(b*Cc + c)*Tt + t)*Vv + vv;
    out[oi] = acc + resid[oi];
}

// ---------------- LayerNorm stats (per batch over CTV) ----------------
// grid = B*32 blocks, 256 threads
__global__ void stats_kernel(const float* __restrict__ x, float* __restrict__ stats) {
    int b = blockIdx.x >> 5; int part = blockIdx.x & 31;
    const float* xb = x + (size_t)b*CTV;
    float s1 = 0.f, s2 = 0.f;
    for (int i = part*256 + threadIdx.x; i < CTV; i += 32*256) {
        float val = xb[i]; s1 += val; s2 += val*val;
    }
    __shared__ float r1[256], r2[256];
    r1[threadIdx.x] = s1; r2[threadIdx.x] = s2;
    __syncthreads();
    for (int o = 128; o > 0; o >>= 1) {
        if (threadIdx.x < o) { r1[threadIdx.x] += r1[threadIdx.x+o]; r2[threadIdx.x] += r2[threadIdx.x+o]; }
        __syncthreads();
    }
    if (threadIdx.x == 0) { atomicAdd(&stats[b*2], r1[0]); atomicAdd(&stats[b*2+1], r2[0]); }
}

// ---------------- LayerNorm apply (+roll via shift) ----------------
// grid = S/256 blocks, 256 threads
__global__ void ln_apply_kernel(const float* __restrict__ x,
                                const float* __restrict__ g,
                                const float* __restrict__ be,
                                const float* __restrict__ stats,
                                float* __restrict__ out,
                                int shift) {
    int idx = blockIdx.x*256 + threadIdx.x;
    if (idx >= S) return;
    int b = idx / CTV; int r = idx % CTV;
    int c = r / TV; int q2 = r % TV; int t = q2 / Vv; int vv = q2 % Vv;
    float mean = stats[b*2] * (1.0f/CTV);
    float var  = stats[b*2+1] * (1.0f/CTV) - mean*mean;
    float rstd = rsqrtf(var + EPSF);
    float val = (x[idx]-mean)*rstd*g[r] + be[r];
    int tout = (t - shift + Tt) % Tt;   // roll(-shift): input t lands at t-shift
    size_t oidx = ((size_t)(b*Cc + c)*Tt + tout)*Vv + vv;
    out[oidx] = val;
}

// ---------------- FFN fused (relu(x@W1+b1)@W2+b2 + x), 16 positions/block ----------------
// grid = B*T*V/16 blocks, 256 threads
__global__ __launch_bounds__(256) void ffn_kernel(const float* __restrict__ xin,
        const float* __restrict__ w1, const float* __restrict__ b1,
        const float* __restrict__ w2, const float* __restrict__ b2,
        float* __restrict__ out) {
    __shared__ float xs[16][Cc];     // 4 KB
    __shared__ float hs[16][256];    // 16 KB
    int tid = threadIdx.x;
    int p0 = blockIdx.x * 16;
    for (int i = tid; i < 16*Cc; i += 256) {
        int pl = i >> 6; int c = i & 63;
        int p = p0 + pl;
        int b = p / TV; int r = p % TV;
        xs[pl][c] = xin[(size_t)(b*Cc + c)*TV + r];
    }
    __syncthreads();
    // phase 1: hidden [16][256]; iteration j handles position j, d = tid
    for (int j = 0; j < 16; ++j) {
        float h = b1[tid];
        #pragma unroll 8
        for (int c = 0; c < Cc; ++c) h += xs[j][c] * w1[c*256 + tid];
        hs[j][tid] = fmaxf(h, 0.f);
    }
    __syncthreads();
    // phase 2: out [16][64]
    for (int j = 0; j < 4; ++j) {
        int idx = tid + j*256;
        int pl = idx >> 6; int c = idx & 63;
        float acc = b2[c];
        #pragma unroll 8
        for (int d = 0; d < 256; ++d) acc += hs[pl][d] * w2[d*Cc + c];
        int p = p0 + pl;
        int b = p / TV; int r = p % TV;
        size_t oi = (size_t)(b*Cc + c)*TV + r;
        out[oi] = acc + xs[pl][c];
    }
}

extern "C" void kernel_launch(void* const* d_in, const int* in_sizes, int n_in,
                              void* d_out, int out_size, void* d_ws, size_t ws_size,
                              hipStream_t stream) {
    const float* xin = (const float*)d_in[0];

    float* bufA  = (float*)d_ws;
    float* bufB  = bufA + S;
    float* q     = bufB + S;
    float* k     = q + S;
    float* v     = k + S;
    float* att   = v + S;
    float* stats = att + S;   // 64 floats

    zero_stats_kernel<<<1, 64, 0, stream>>>(stats);

    for (int blk = 0; blk < 2; ++blk) {
        int o = 1 + blk*12;
        const float* qkvw = (const float*)d_in[o+0];
        const float* qkvb = (const float*)d_in[o+1];
        const float* pw   = (const float*)d_in[o+2];
        const float* pb   = (const float*)d_in[o+3];
        const float* fw1  = (const float*)d_in[o+4];
        const float* fb1  = (const float*)d_in[o+5];
        const float* fw2  = (const float*)d_in[o+6];
        const float* fb2  = (const float*)d_in[o+7];
        const float* g1   = (const float*)d_in[o+8];
        const float* be1  = (const float*)d_in[o+9];
        const float* g2   = (const float*)d_in[o+10];
        const float* be2  = (const float*)d_in[o+11];
        float* st1 = stats + blk*32;
        float* st2 = st1 + 16;

        const float* src = (blk == 0) ? xin : bufA;

        qkv_kernel<<<Bb*TV, 192, 0, stream>>>(src, qkvw, qkvb, q, k, v);
        attn_kernel<<<Bb*NW*Hh*4, 256, 0, stream>>>(q, k, v, att);
        proj_kernel<<<Bb*TV/4, 256, 0, stream>>>(att, pw, pb, src, bufB);
        stats_kernel<<<Bb*32, 256, 0, stream>>>(bufB, st1);
        ln_apply_kernel<<<S/256, 256, 0, stream>>>(bufB, g1, be1, st1, bufA, 0);
        ffn_kernel<<<Bb*TV/16, 256, 0, stream>>>(bufA, fw1, fb1, fw2, fb2, bufB);
        stats_kernel<<<Bb*32, 256, 0, stream>>>(bufB, st2);
        bool fin = (blk == 1);
        ln_apply_kernel<<<S/256, 256, 0, stream>>>(bufB, g2, be2, st2,
                                                   fin ? (float*)d_out : bufA,
                                                   WSZ/2);
    }
}

// Round 3
// 667.405 us; speedup vs baseline: 1.5332x; 1.5332x over previous
//
#include <hip/hip_runtime.h>
#include <hip/hip_bf16.h>

#define Bb  8
#define Cc  64
#define Tt  16
#define Vv  207
#define Hh  8
#define DH  8
#define NW  4
#define WSZ 4
#define Nn  (WSZ*Vv)       // 828
#define NP  832            // padded window length (52*16)
#define TV  (Tt*Vv)        // 3312
#define CTV (Cc*Tt*Vv)     // 211968
#define S   (Bb*CTV)       // 1695744
#define NBWH (Bb*NW*Hh)    // 256
#define EPSF 1e-5f

typedef __attribute__((ext_vector_type(4))) short bf16x4;
typedef __attribute__((ext_vector_type(4))) float f32x4;

static __device__ __forceinline__ short f2bf(float f) {
    union { float f; unsigned u; } v; v.f = f;
    unsigned r = (v.u + 0x7FFFu + ((v.u >> 16) & 1u)) >> 16;  // RNE
    return (short)r;
}

__global__ void zero_stats_kernel(float* stats) {
    stats[threadIdx.x] = 0.f;   // 64 floats: 4 LN slots x (B*2)
}

// zero the n-pad regions of q/k (rows 828..831) and vT (cols 828..831)
__global__ void zero_pads_kernel(short* __restrict__ qb, short* __restrict__ kb,
                                 short* __restrict__ vtb) {
    int i = blockIdx.x*256 + threadIdx.x;   // 32 blocks -> 8192
    if (i < NBWH*4*8) {
        int bwh = i >> 5; int rest = i & 31;
        int n = Nn + (rest >> 3); int d = rest & 7;
        size_t idx = ((size_t)bwh*NP + n)*8 + d;
        qb[idx] = 0; kb[idx] = 0;
        int d2 = rest >> 2; int n2 = Nn + (rest & 3);
        vtb[((size_t)bwh*8 + d2)*NP + n2] = 0;
    }
}

// ---------------- QKV: register-column GEMM, 24 positions/block ----------------
// grid = 26496/24 = 1104 blocks, 192 threads
__global__ __launch_bounds__(192) void qkv_kernel(const float* __restrict__ xin,
        const float* __restrict__ w, const float* __restrict__ bias,
        short* __restrict__ qb, short* __restrict__ kb, short* __restrict__ vtb) {
    __shared__ float xs[24][68];
    int tid = threadIdx.x;
    float wcol[64];
    #pragma unroll
    for (int c = 0; c < 64; ++c) wcol[c] = w[c*192 + tid];
    float bv = bias[tid];
    int p0 = blockIdx.x * 24;
    int b = p0 / TV;           // 24 | TV so whole block is one b
    int r0 = p0 % TV;
    const float* xb = xin + (size_t)b*CTV;
    for (int i = tid; i < 24*64; i += 192) {
        int g = i % 24; int c = i / 24;
        xs[g][c] = xb[(size_t)c*TV + r0 + g];
    }
    __syncthreads();
    int which = tid >> 6; int cc = tid & 63;
    int h = cc >> 3; int d = cc & 7;
    for (int g = 0; g < 24; ++g) {
        float acc = bv;
        const float4* xv = (const float4*)xs[g];
        #pragma unroll
        for (int c4 = 0; c4 < 16; ++c4) {
            float4 x4 = xv[c4];
            acc += x4.x*wcol[c4*4+0] + x4.y*wcol[c4*4+1]
                 + x4.z*wcol[c4*4+2] + x4.w*wcol[c4*4+3];
        }
        int r = r0 + g;
        int t = r / Vv; int vv = r % Vv;
        int w_ = t >> 2; int tw = t & 3;
        int n = tw*Vv + vv;
        int bwh = (b*NW + w_)*Hh + h;
        if (which == 0)      qb[((size_t)bwh*NP + n)*8 + d] = f2bf(acc * 0.35355339059327373f);
        else if (which == 1) kb[((size_t)bwh*NP + n)*8 + d] = f2bf(acc);
        else                 vtb[((size_t)bwh*8 + d)*NP + n] = f2bf(acc);
    }
}

// ---------------- Flash MFMA attention ----------------
// grid = 256 bwh * 13 mtile-groups = 3328 blocks, 256 threads (4 waves, 1 m-tile each)
// S^T tile = MFMA(A=K,B=Q^T); P^T=exp(S^T) in C-layout == B-operand layout;
// O^T += MFMA(A=V^T (ones at d=8), B=P^T); l[m] = O^T[8][m].
__global__ __launch_bounds__(256) void attn_kernel(const short* __restrict__ qb,
        const short* __restrict__ kb, const short* __restrict__ vtb,
        float* __restrict__ att) {
    int bwh = blockIdx.x / 13;
    int mtg = blockIdx.x % 13;
    int lane = threadIdx.x & 63;
    int wv = threadIdx.x >> 6;
    int mtile = mtg*4 + wv;
    int quad = lane >> 4;
    int l15 = lane & 15;
    const short* qbase = qb + (size_t)bwh*NP*8;
    const short* kbase = kb + (size_t)bwh*NP*8;
    const short* vbase = vtb + (size_t)bwh*8*NP;

    bf16x4 aq = {0,0,0,0};
    if (quad < 2) aq = *(const bf16x4*)(qbase + (mtile*16 + l15)*8 + quad*4);

    const short ONE = 0x3F80;   // bf16(1.0)
    f32x4 oacc = {0.f,0.f,0.f,0.f};
    for (int nt = 0; nt < 52; ++nt) {
        bf16x4 ak = {0,0,0,0};
        if (quad < 2) ak = *(const bf16x4*)(kbase + (nt*16 + l15)*8 + quad*4);
        f32x4 s = __builtin_amdgcn_mfma_f32_16x16x16bf16_1k(
                      ak, aq, (f32x4){0.f,0.f,0.f,0.f}, 0, 0, 0);
        float p0 = __expf(s[0]);
        float p1 = __expf(s[1]);
        float p2 = __expf(s[2]);
        float p3 = __expf(s[3]);
        if (nt == 51) {          // mask pad keys n>=828 (wave-uniform branch)
            int nb = nt*16 + quad*4;
            if (nb+0 >= Nn) p0 = 0.f;
            if (nb+1 >= Nn) p1 = 0.f;
            if (nb+2 >= Nn) p2 = 0.f;
            if (nb+3 >= Nn) p3 = 0.f;
        }
        bf16x4 pb;
        pb[0] = f2bf(p0); pb[1] = f2bf(p1); pb[2] = f2bf(p2); pb[3] = f2bf(p3);
        bf16x4 av;
        if (l15 < 8)        av = *(const bf16x4*)(vbase + l15*NP + nt*16 + quad*4);
        else if (l15 == 8)  av = (bf16x4){ONE, ONE, ONE, ONE};
        else                av = (bf16x4){0,0,0,0};
        oacc = __builtin_amdgcn_mfma_f32_16x16x16bf16_1k(av, pb, oacc, 0, 0, 0);
    }
    // l[m] sits in lane 32+m, element 0 (row d=8)
    float lsum = __shfl(oacc[0], 32 + l15, 64);
    float linv = 1.f / lsum;
    int m = mtile*16 + l15;
    if (quad < 2 && m < Nn) {
        int h = bwh & 7; int bw = bwh >> 3;
        float* dst = att + ((size_t)bw*Nn + m)*Cc + h*DH + quad*4;
        dst[0] = oacc[0]*linv;
        dst[1] = oacc[1]*linv;
        dst[2] = oacc[2]*linv;
        dst[3] = oacc[3]*linv;
    }
}

// ---------------- Proj + residual: register-column, 32 positions/block ----------------
// grid = 26496/32 = 828 blocks, 256 threads (4 waves x 8 positions)
__global__ __launch_bounds__(256) void proj_kernel(const float* __restrict__ att,
        const float* __restrict__ wo, const float* __restrict__ bo,
        const float* __restrict__ resid, float* __restrict__ out) {
    __shared__ float xs[32][68];
    int tid = threadIdx.x;
    int c = tid & 63; int wv = tid >> 6;
    float wcol[64];
    #pragma unroll
    for (int i = 0; i < 64; ++i) wcol[i] = wo[i*Cc + c];
    float bv = bo[c];
    int p0 = blockIdx.x * 32;
    for (int i = tid; i < 32*64; i += 256) {
        int g = i >> 6; int cc2 = i & 63;
        int p = p0 + g;
        int b = p / TV; int r = p % TV;
        int t = r / Vv; int vv = r % Vv;
        int w_ = t >> 2; int tw = t & 3;
        int n = tw*Vv + vv;
        int bw = b*NW + w_;
        xs[g][cc2] = att[((size_t)bw*Nn + n)*Cc + cc2];
    }
    __syncthreads();
    for (int gi = 0; gi < 8; ++gi) {
        int g = wv*8 + gi;
        float acc = bv;
        const float4* xv = (const float4*)xs[g];
        #pragma unroll
        for (int c4 = 0; c4 < 16; ++c4) {
            float4 x4 = xv[c4];
            acc += x4.x*wcol[c4*4+0] + x4.y*wcol[c4*4+1]
                 + x4.z*wcol[c4*4+2] + x4.w*wcol[c4*4+3];
        }
        int p = p0 + g;
        int b = p / TV; int r = p % TV;
        size_t oi = (size_t)b*CTV + (size_t)c*TV + r;
        out[oi] = acc + resid[oi];
    }
}

// ---------------- LayerNorm stats (per batch over CTV) ----------------
__global__ void stats_kernel(const float* __restrict__ x, float* __restrict__ stats) {
    int b = blockIdx.x >> 5; int part = blockIdx.x & 31;
    const float* xb = x + (size_t)b*CTV;
    float s1 = 0.f, s2 = 0.f;
    for (int i = part*256 + threadIdx.x; i < CTV; i += 32*256) {
        float val = xb[i]; s1 += val; s2 += val*val;
    }
    __shared__ float r1[256], r2[256];
    r1[threadIdx.x] = s1; r2[threadIdx.x] = s2;
    __syncthreads();
    for (int o = 128; o > 0; o >>= 1) {
        if (threadIdx.x < o) { r1[threadIdx.x] += r1[threadIdx.x+o]; r2[threadIdx.x] += r2[threadIdx.x+o]; }
        __syncthreads();
    }
    if (threadIdx.x == 0) { atomicAdd(&stats[b*2], r1[0]); atomicAdd(&stats[b*2+1], r2[0]); }
}

// ---------------- LayerNorm apply (+roll via shift) ----------------
__global__ void ln_apply_kernel(const float* __restrict__ x,
                                const float* __restrict__ g,
                                const float* __restrict__ be,
                                const float* __restrict__ stats,
                                float* __restrict__ out,
                                int shift) {
    int idx = blockIdx.x*256 + threadIdx.x;
    if (idx >= S) return;
    int b = idx / CTV; int r = idx % CTV;
    int c = r / TV; int q2 = r % TV; int t = q2 / Vv; int vv = q2 % Vv;
    float mean = stats[b*2] * (1.0f/CTV);
    float var  = stats[b*2+1] * (1.0f/CTV) - mean*mean;
    float rstd = rsqrtf(var + EPSF);
    float val = (x[idx]-mean)*rstd*g[r] + be[r];
    int tout = (t - shift + Tt) % Tt;   // roll(-shift)
    size_t oidx = ((size_t)(b*Cc + c)*Tt + tout)*Vv + vv;
    out[oidx] = val;
}

// ---------------- FFN fused (relu(x@W1+b1)@W2+b2 + x), 16 positions/block ----------------
__global__ __launch_bounds__(256) void ffn_kernel(const float* __restrict__ xin,
        const float* __restrict__ w1, const float* __restrict__ b1,
        const float* __restrict__ w2, const float* __restrict__ b2,
        float* __restrict__ out) {
    __shared__ float xs[16][Cc];
    __shared__ float hs[16][256];
    int tid = threadIdx.x;
    int p0 = blockIdx.x * 16;
    for (int i = tid; i < 16*Cc; i += 256) {
        int pl = i >> 6; int c = i & 63;
        int p = p0 + pl;
        int b = p / TV; int r = p % TV;
        xs[pl][c] = xin[(size_t)(b*Cc + c)*TV + r];
    }
    __syncthreads();
    for (int j = 0; j < 16; ++j) {
        float h = b1[tid];
        #pragma unroll 8
        for (int c = 0; c < Cc; ++c) h += xs[j][c] * w1[c*256 + tid];
        hs[j][tid] = fmaxf(h, 0.f);
    }
    __syncthreads();
    for (int j = 0; j < 4; ++j) {
        int idx = tid + j*256;
        int pl = idx >> 6; int c = idx & 63;
        float acc = b2[c];
        #pragma unroll 8
        for (int d = 0; d < 256; ++d) acc += hs[pl][d] * w2[d*Cc + c];
        int p = p0 + pl;
        int b = p / TV; int r = p % TV;
        size_t oi = (size_t)(b*Cc + c)*TV + r;
        out[oi] = acc + xs[pl][c];
    }
}

extern "C" void kernel_launch(void* const* d_in, const int* in_sizes, int n_in,
                              void* d_out, int out_size, void* d_ws, size_t ws_size,
                              hipStream_t stream) {
    const float* xin = (const float*)d_in[0];

    float* bufA  = (float*)d_ws;
    float* bufB  = bufA + S;
    float* att   = bufB + S;
    float* stats = att + S;          // 64 floats
    short* qb    = (short*)(stats + 64);
    short* kb    = qb + (size_t)NBWH*NP*8;
    short* vtb   = kb + (size_t)NBWH*NP*8;

    zero_stats_kernel<<<1, 64, 0, stream>>>(stats);
    zero_pads_kernel<<<32, 256, 0, stream>>>(qb, kb, vtb);

    for (int blk = 0; blk < 2; ++blk) {
        int o = 1 + blk*12;
        const float* qkvw = (const float*)d_in[o+0];
        const float* qkvb = (const float*)d_in[o+1];
        const float* pw   = (const float*)d_in[o+2];
        const float* pb   = (const float*)d_in[o+3];
        const float* fw1  = (const float*)d_in[o+4];
        const float* fb1  = (const float*)d_in[o+5];
        const float* fw2  = (const float*)d_in[o+6];
        const float* fb2  = (const float*)d_in[o+7];
        const float* g1   = (const float*)d_in[o+8];
        const float* be1  = (const float*)d_in[o+9];
        const float* g2   = (const float*)d_in[o+10];
        const float* be2  = (const float*)d_in[o+11];
        float* st1 = stats + blk*32;
        float* st2 = st1 + 16;

        const float* src = (blk == 0) ? xin : bufA;

        qkv_kernel<<<Bb*TV/24, 192, 0, stream>>>(src, qkvw, qkvb, qb, kb, vtb);
        attn_kernel<<<NBWH*13, 256, 0, stream>>>(qb, kb, vtb, att);
        proj_kernel<<<Bb*TV/32, 256, 0, stream>>>(att, pw, pb, src, bufB);
        stats_kernel<<<Bb*32, 256, 0, stream>>>(bufB, st1);
        ln_apply_kernel<<<S/256, 256, 0, stream>>>(bufB, g1, be1, st1, bufA, 0);
        ffn_kernel<<<Bb*TV/16, 256, 0, stream>>>(bufA, fw1, fb1, fw2, fb2, bufB);
        stats_kernel<<<Bb*32, 256, 0, stream>>>(bufB, st2);
        bool fin = (blk == 1);
        ln_apply_kernel<<<S/256, 256, 0, stream>>>(bufB, g2, be2, st2,
                                                   fin ? (float*)d_out : bufA,
                                                   WSZ/2);
    }
}

// Round 4
// 460.680 us; speedup vs baseline: 2.2212x; 1.4487x over previous
//
#include <hip/hip_runtime.h>
#include <hip/hip_bf16.h>

#define Bb  8
#define Cc  64
#define Tt  16
#define Vv  207
#define Hh  8
#define DH  8
#define NW  4
#define WSZ 4
#define Nn  (WSZ*Vv)       // 828
#define NP  832            // padded window length (52*16)
#define TV  (Tt*Vv)        // 3312
#define CTV (Cc*Tt*Vv)     // 211968
#define S   (Bb*CTV)       // 1695744
#define NBWH (Bb*NW*Hh)    // 256
#define EPSF 1e-5f

typedef __attribute__((ext_vector_type(4))) short bf16x4;
typedef __attribute__((ext_vector_type(4))) float f32x4;

static __device__ __forceinline__ short f2bf(float f) {
    union { float f; unsigned u; } v; v.f = f;
    unsigned r = (v.u + 0x7FFFu + ((v.u >> 16) & 1u)) >> 16;  // RNE
    return (short)r;
}

__global__ void zero_stats_kernel(float* stats) {
    stats[threadIdx.x] = 0.f;   // 64 floats: 4 LN slots x (B*2)
}

// zero the n-pad regions of q/k (rows 828..831) and vT (cols 828..831)
__global__ void zero_pads_kernel(short* __restrict__ qb, short* __restrict__ kb,
                                 short* __restrict__ vtb) {
    int i = blockIdx.x*256 + threadIdx.x;   // 32 blocks -> 8192
    if (i < NBWH*4*8) {
        int bwh = i >> 5; int rest = i & 31;
        int n = Nn + (rest >> 3); int d = rest & 7;
        size_t idx = ((size_t)bwh*NP + n)*8 + d;
        qb[idx] = 0; kb[idx] = 0;
        int d2 = rest >> 2; int n2 = Nn + (rest & 3);
        vtb[((size_t)bwh*8 + d2)*NP + n2] = 0;
    }
}

// ---------------- QKV: register-column GEMM, 24 positions/block ----------------
// grid = 26496/24 = 1104 blocks, 192 threads
__global__ __launch_bounds__(192) void qkv_kernel(const float* __restrict__ xin,
        const float* __restrict__ w, const float* __restrict__ bias,
        short* __restrict__ qb, short* __restrict__ kb, short* __restrict__ vtb) {
    __shared__ float xs[24][68];
    int tid = threadIdx.x;
    float wcol[64];
    #pragma unroll
    for (int c = 0; c < 64; ++c) wcol[c] = w[c*192 + tid];
    float bv = bias[tid];
    int p0 = blockIdx.x * 24;
    int b = p0 / TV;           // 24 | TV so whole block is one b
    int r0 = p0 % TV;
    const float* xb = xin + (size_t)b*CTV;
    for (int i = tid; i < 24*64; i += 192) {
        int g = i % 24; int c = i / 24;
        xs[g][c] = xb[(size_t)c*TV + r0 + g];
    }
    __syncthreads();
    int which = tid >> 6; int cc = tid & 63;
    int h = cc >> 3; int d = cc & 7;
    for (int g = 0; g < 24; ++g) {
        float acc = bv;
        const float4* xv = (const float4*)xs[g];
        #pragma unroll
        for (int c4 = 0; c4 < 16; ++c4) {
            float4 x4 = xv[c4];
            acc += x4.x*wcol[c4*4+0] + x4.y*wcol[c4*4+1]
                 + x4.z*wcol[c4*4+2] + x4.w*wcol[c4*4+3];
        }
        int r = r0 + g;
        int t = r / Vv; int vv = r % Vv;
        int w_ = t >> 2; int tw = t & 3;
        int n = tw*Vv + vv;
        int bwh = (b*NW + w_)*Hh + h;
        if (which == 0)      qb[((size_t)bwh*NP + n)*8 + d] = f2bf(acc * 0.35355339059327373f);
        else if (which == 1) kb[((size_t)bwh*NP + n)*8 + d] = f2bf(acc);
        else                 vtb[((size_t)bwh*8 + d)*NP + n] = f2bf(acc);
    }
}

// ---------------- Flash MFMA attention ----------------
// grid = 256 bwh * 13 mtile-groups = 3328 blocks, 256 threads (4 waves, 1 m-tile each)
__global__ __launch_bounds__(256) void attn_kernel(const short* __restrict__ qb,
        const short* __restrict__ kb, const short* __restrict__ vtb,
        float* __restrict__ att) {
    int bwh = blockIdx.x / 13;
    int mtg = blockIdx.x % 13;
    int lane = threadIdx.x & 63;
    int wv = threadIdx.x >> 6;
    int mtile = mtg*4 + wv;
    int quad = lane >> 4;
    int l15 = lane & 15;
    const short* qbase = qb + (size_t)bwh*NP*8;
    const short* kbase = kb + (size_t)bwh*NP*8;
    const short* vbase = vtb + (size_t)bwh*8*NP;

    bf16x4 aq = {0,0,0,0};
    if (quad < 2) aq = *(const bf16x4*)(qbase + (mtile*16 + l15)*8 + quad*4);

    const short ONE = 0x3F80;   // bf16(1.0)
    f32x4 oacc = {0.f,0.f,0.f,0.f};
    for (int nt = 0; nt < 52; ++nt) {
        bf16x4 ak = {0,0,0,0};
        if (quad < 2) ak = *(const bf16x4*)(kbase + (nt*16 + l15)*8 + quad*4);
        f32x4 s = __builtin_amdgcn_mfma_f32_16x16x16bf16_1k(
                      ak, aq, (f32x4){0.f,0.f,0.f,0.f}, 0, 0, 0);
        float p0 = __expf(s[0]);
        float p1 = __expf(s[1]);
        float p2 = __expf(s[2]);
        float p3 = __expf(s[3]);
        if (nt == 51) {          // mask pad keys n>=828 (wave-uniform branch)
            int nb = nt*16 + quad*4;
            if (nb+0 >= Nn) p0 = 0.f;
            if (nb+1 >= Nn) p1 = 0.f;
            if (nb+2 >= Nn) p2 = 0.f;
            if (nb+3 >= Nn) p3 = 0.f;
        }
        bf16x4 pb;
        pb[0] = f2bf(p0); pb[1] = f2bf(p1); pb[2] = f2bf(p2); pb[3] = f2bf(p3);
        bf16x4 av;
        if (l15 < 8)        av = *(const bf16x4*)(vbase + l15*NP + nt*16 + quad*4);
        else if (l15 == 8)  av = (bf16x4){ONE, ONE, ONE, ONE};
        else                av = (bf16x4){0,0,0,0};
        oacc = __builtin_amdgcn_mfma_f32_16x16x16bf16_1k(av, pb, oacc, 0, 0, 0);
    }
    float lsum = __shfl(oacc[0], 32 + l15, 64);
    float linv = 1.f / lsum;
    int m = mtile*16 + l15;
    if (quad < 2 && m < Nn) {
        int h = bwh & 7; int bw = bwh >> 3;
        float* dst = att + ((size_t)bw*Nn + m)*Cc + h*DH + quad*4;
        dst[0] = oacc[0]*linv;
        dst[1] = oacc[1]*linv;
        dst[2] = oacc[2]*linv;
        dst[3] = oacc[3]*linv;
    }
}

// ---------------- Proj + residual: register-column, 32 positions/block ----------------
__global__ __launch_bounds__(256) void proj_kernel(const float* __restrict__ att,
        const float* __restrict__ wo, const float* __restrict__ bo,
        const float* __restrict__ resid, float* __restrict__ out) {
    __shared__ float xs[32][68];
    int tid = threadIdx.x;
    int c = tid & 63; int wv = tid >> 6;
    float wcol[64];
    #pragma unroll
    for (int i = 0; i < 64; ++i) wcol[i] = wo[i*Cc + c];
    float bv = bo[c];
    int p0 = blockIdx.x * 32;
    for (int i = tid; i < 32*64; i += 256) {
        int g = i >> 6; int cc2 = i & 63;
        int p = p0 + g;
        int b = p / TV; int r = p % TV;
        int t = r / Vv; int vv = r % Vv;
        int w_ = t >> 2; int tw = t & 3;
        int n = tw*Vv + vv;
        int bw = b*NW + w_;
        xs[g][cc2] = att[((size_t)bw*Nn + n)*Cc + cc2];
    }
    __syncthreads();
    for (int gi = 0; gi < 8; ++gi) {
        int g = wv*8 + gi;
        float acc = bv;
        const float4* xv = (const float4*)xs[g];
        #pragma unroll
        for (int c4 = 0; c4 < 16; ++c4) {
            float4 x4 = xv[c4];
            acc += x4.x*wcol[c4*4+0] + x4.y*wcol[c4*4+1]
                 + x4.z*wcol[c4*4+2] + x4.w*wcol[c4*4+3];
        }
        int p = p0 + g;
        int b = p / TV; int r = p % TV;
        size_t oi = (size_t)b*CTV + (size_t)c*TV + r;
        out[oi] = acc + resid[oi];
    }
}

// ---------------- LayerNorm stats (per batch over CTV) ----------------
__global__ void stats_kernel(const float* __restrict__ x, float* __restrict__ stats) {
    int b = blockIdx.x >> 5; int part = blockIdx.x & 31;
    const float* xb = x + (size_t)b*CTV;
    float s1 = 0.f, s2 = 0.f;
    for (int i = part*256 + threadIdx.x; i < CTV; i += 32*256) {
        float val = xb[i]; s1 += val; s2 += val*val;
    }
    __shared__ float r1[256], r2[256];
    r1[threadIdx.x] = s1; r2[threadIdx.x] = s2;
    __syncthreads();
    for (int o = 128; o > 0; o >>= 1) {
        if (threadIdx.x < o) { r1[threadIdx.x] += r1[threadIdx.x+o]; r2[threadIdx.x] += r2[threadIdx.x+o]; }
        __syncthreads();
    }
    if (threadIdx.x == 0) { atomicAdd(&stats[b*2], r1[0]); atomicAdd(&stats[b*2+1], r2[0]); }
}

// ---------------- LayerNorm apply (+roll via shift) ----------------
__global__ void ln_apply_kernel(const float* __restrict__ x,
                                const float* __restrict__ g,
                                const float* __restrict__ be,
                                const float* __restrict__ stats,
                                float* __restrict__ out,
                                int shift) {
    int idx = blockIdx.x*256 + threadIdx.x;
    if (idx >= S) return;
    int b = idx / CTV; int r = idx % CTV;
    int c = r / TV; int q2 = r % TV; int t = q2 / Vv; int vv = q2 % Vv;
    float mean = stats[b*2] * (1.0f/CTV);
    float var  = stats[b*2+1] * (1.0f/CTV) - mean*mean;
    float rstd = rsqrtf(var + EPSF);
    float val = (x[idx]-mean)*rstd*g[r] + be[r];
    int tout = (t - shift + Tt) % Tt;   // roll(-shift)
    size_t oidx = ((size_t)(b*Cc + c)*Tt + tout)*Vv + vv;
    out[oidx] = val;
}

// ---------------- FFN: MFMA chained two-stage GEMM ----------------
// grid = 26496/64 = 414 blocks, 256 threads (4 waves, 16 positions each).
// Stage 1: H^T tile = mfma(W1^T frag, X frag) + b1, relu -> bf16 (C-layout == B-op layout)
// Stage 2: O^T tile = sum_nt mfma(W2^T frag, P frag); epilogue adds b2 + fp32 residual.
__global__ __launch_bounds__(256) void ffn_kernel(const float* __restrict__ xin,
        const float* __restrict__ w1, const float* __restrict__ b1,
        const float* __restrict__ w2, const float* __restrict__ b2,
        float* __restrict__ out) {
    __shared__ short w1s[4096*4];   // [(nt*4+kc)*64+lane] bf16x4 frags, 32 KB
    __shared__ short w2s[4096*4];   // [(nt*4+ct)*64+lane] bf16x4 frags, 32 KB
    __shared__ short xsf[1024*4];   // [(wv*4+kc)*64+lane] bf16x4 frags, 8 KB
    __shared__ float b1s[256];
    __shared__ float b2s[64];
    int tid = threadIdx.x;
    int p0 = blockIdx.x * 64;

    // stage W1 fragments: lane holds W1^T[d=nt*16+l15][c=kc*16+quad*4+j]
    for (int s2 = tid; s2 < 4096; s2 += 256) {
        int nt = s2 >> 8; int kc = (s2 >> 6) & 3; int ln = s2 & 63;
        int l15 = ln & 15; int quad = ln >> 4;
        bf16x4 f;
        #pragma unroll
        for (int j = 0; j < 4; ++j)
            f[j] = f2bf(w1[(kc*16 + quad*4 + j)*256 + nt*16 + l15]);
        *((bf16x4*)&w1s[s2*4]) = f;
    }
    // stage W2 fragments: lane holds W2^T[c_out=ct*16+l15][d=nt*16+quad*4+j]
    for (int s2 = tid; s2 < 4096; s2 += 256) {
        int nt = s2 >> 8; int ct = (s2 >> 6) & 3; int ln = s2 & 63;
        int l15 = ln & 15; int quad = ln >> 4;
        bf16x4 f;
        #pragma unroll
        for (int j = 0; j < 4; ++j)
            f[j] = f2bf(w2[(nt*16 + quad*4 + j)*64 + ct*16 + l15]);
        *((bf16x4*)&w2s[s2*4]) = f;
    }
    // stage X fragments: lane holds X[m=wv*16+l15][c=kc*16+quad*4+j]
    for (int s2 = tid; s2 < 1024; s2 += 256) {
        int wv2 = s2 >> 8; int kc = (s2 >> 6) & 3; int ln = s2 & 63;
        int l15 = ln & 15; int quad = ln >> 4;
        int p = p0 + wv2*16 + l15;
        int b = p / TV; int r = p % TV;
        bf16x4 f;
        #pragma unroll
        for (int j = 0; j < 4; ++j)
            f[j] = f2bf(xin[(size_t)b*CTV + (size_t)(kc*16 + quad*4 + j)*TV + r]);
        *((bf16x4*)&xsf[s2*4]) = f;
    }
    b1s[tid] = b1[tid];
    if (tid < 64) b2s[tid] = b2[tid];
    __syncthreads();

    int lane = tid & 63; int wv = tid >> 6;
    int l15 = lane & 15; int quad = lane >> 4;
    bf16x4 xf[4];
    #pragma unroll
    for (int kc = 0; kc < 4; ++kc)
        xf[kc] = *((const bf16x4*)&xsf[((wv*4 + kc)*64 + lane)*4]);

    f32x4 oacc[4];
    #pragma unroll
    for (int ct = 0; ct < 4; ++ct) oacc[ct] = (f32x4){0.f,0.f,0.f,0.f};

    for (int nt = 0; nt < 16; ++nt) {
        float4 bb = *((const float4*)&b1s[nt*16 + quad*4]);
        f32x4 acc = {bb.x, bb.y, bb.z, bb.w};
        #pragma unroll
        for (int kc = 0; kc < 4; ++kc) {
            bf16x4 wf = *((const bf16x4*)&w1s[((nt*4 + kc)*64 + lane)*4]);
            acc = __builtin_amdgcn_mfma_f32_16x16x16bf16_1k(wf, xf[kc], acc, 0, 0, 0);
        }
        bf16x4 pf;
        #pragma unroll
        for (int j = 0; j < 4; ++j) pf[j] = f2bf(fmaxf(acc[j], 0.f));
        #pragma unroll
        for (int ct = 0; ct < 4; ++ct) {
            bf16x4 wf2 = *((const bf16x4*)&w2s[((nt*4 + ct)*64 + lane)*4]);
            oacc[ct] = __builtin_amdgcn_mfma_f32_16x16x16bf16_1k(wf2, pf, oacc[ct], 0, 0, 0);
        }
    }
    // epilogue: D2 row=c_out(quad*4+reg within ct*16), col=m(l15)
    int p = p0 + wv*16 + l15;
    int b = p / TV; int r = p % TV;
    #pragma unroll
    for (int ct = 0; ct < 4; ++ct) {
        #pragma unroll
        for (int j = 0; j < 4; ++j) {
            int c_out = ct*16 + quad*4 + j;
            size_t oi = (size_t)b*CTV + (size_t)c_out*TV + r;
            out[oi] = oacc[ct][j] + b2s[c_out] + xin[oi];
        }
    }
}

extern "C" void kernel_launch(void* const* d_in, const int* in_sizes, int n_in,
                              void* d_out, int out_size, void* d_ws, size_t ws_size,
                              hipStream_t stream) {
    const float* xin = (const float*)d_in[0];

    float* bufA  = (float*)d_ws;
    float* bufB  = bufA + S;
    float* att   = bufB + S;
    float* stats = att + S;          // 64 floats
    short* qb    = (short*)(stats + 64);
    short* kb    = qb + (size_t)NBWH*NP*8;
    short* vtb   = kb + (size_t)NBWH*NP*8;

    zero_stats_kernel<<<1, 64, 0, stream>>>(stats);
    zero_pads_kernel<<<32, 256, 0, stream>>>(qb, kb, vtb);

    for (int blk = 0; blk < 2; ++blk) {
        int o = 1 + blk*12;
        const float* qkvw = (const float*)d_in[o+0];
        const float* qkvb = (const float*)d_in[o+1];
        const float* pw   = (const float*)d_in[o+2];
        const float* pb   = (const float*)d_in[o+3];
        const float* fw1  = (const float*)d_in[o+4];
        const float* fb1  = (const float*)d_in[o+5];
        const float* fw2  = (const float*)d_in[o+6];
        const float* fb2  = (const float*)d_in[o+7];
        const float* g1   = (const float*)d_in[o+8];
        const float* be1  = (const float*)d_in[o+9];
        const float* g2   = (const float*)d_in[o+10];
        const float* be2  = (const float*)d_in[o+11];
        float* st1 = stats + blk*32;
        float* st2 = st1 + 16;

        const float* src = (blk == 0) ? xin : bufA;

        qkv_kernel<<<Bb*TV/24, 192, 0, stream>>>(src, qkvw, qkvb, qb, kb, vtb);
        attn_kernel<<<NBWH*13, 256, 0, stream>>>(qb, kb, vtb, att);
        proj_kernel<<<Bb*TV/32, 256, 0, stream>>>(att, pw, pb, src, bufB);
        stats_kernel<<<Bb*32, 256, 0, stream>>>(bufB, st1);
        ln_apply_kernel<<<S/256, 256, 0, stream>>>(bufB, g1, be1, st1, bufA, 0);
        ffn_kernel<<<Bb*TV/64, 256, 0, stream>>>(bufA, fw1, fb1, fw2, fb2, bufB);
        stats_kernel<<<Bb*32, 256, 0, stream>>>(bufB, st2);
        bool fin = (blk == 1);
        ln_apply_kernel<<<S/256, 256, 0, stream>>>(bufB, g2, be2, st2,
                                                   fin ? (float*)d_out : bufA,
                                                   WSZ/2);
    }
}

// Round 5
// 409.598 us; speedup vs baseline: 2.4982x; 1.1247x over previous
//
#include <hip/hip_runtime.h>
#include <hip/hip_bf16.h>

#define Bb  8
#define Cc  64
#define Tt  16
#define Vv  207
#define Hh  8
#define DH  8
#define NW  4
#define WSZ 4
#define Nn  (WSZ*Vv)       // 828
#define NP  832            // padded window length (52*16)
#define TV  (Tt*Vv)        // 3312
#define CTV (Cc*Tt*Vv)     // 211968
#define S   (Bb*CTV)       // 1695744
#define NBWH (Bb*NW*Hh)    // 256
#define EPSF 1e-5f
// log2(e)/sqrt(8): folded into Q so softmax uses exp2 directly
#define QSCALE 0.51006971401146f

typedef __attribute__((ext_vector_type(4))) short bf16x4;
typedef __attribute__((ext_vector_type(4))) float f32x4;
typedef __attribute__((ext_vector_type(2))) unsigned int u32x2;

static __device__ __forceinline__ short f2bf(float f) {
    union { float f; unsigned u; } v; v.f = f;
    unsigned r = (v.u + 0x7FFFu + ((v.u >> 16) & 1u)) >> 16;  // RNE
    return (short)r;
}

// cheap pack: round-half-up (bias cancels in softmax; fine for ffn too)
static __device__ __forceinline__ bf16x4 pack4(float a, float b, float c, float d) {
    unsigned ua = __builtin_bit_cast(unsigned, a) + 0x8000u;
    unsigned ub = __builtin_bit_cast(unsigned, b) + 0x8000u;
    unsigned uc = __builtin_bit_cast(unsigned, c) + 0x8000u;
    unsigned ud = __builtin_bit_cast(unsigned, d) + 0x8000u;
    u32x2 t;
    t[0] = (ua >> 16) | (ub & 0xFFFF0000u);
    t[1] = (uc >> 16) | (ud & 0xFFFF0000u);
    return __builtin_bit_cast(bf16x4, t);
}

// ---------------- prep: zero stats, fill K/V pad regions ----------------
// kb layout [bwh][NP][16] (d=8..15 zero), vtb layout [bwh][16][NP]
// (row 8 = 1.0 for the l-sum trick, rows 9..15 = 0), q/k/v n-pads zero.
__global__ void prep_kernel(short* __restrict__ qb, short* __restrict__ kb,
                            short* __restrict__ vtb, float* __restrict__ stats) {
    int i = blockIdx.x*256 + threadIdx.x;
    if (i < 64) stats[i] = 0.f;
    if (i < NBWH*NP*8) {
        int bwh = i / (NP*8); int rest = i % (NP*8);
        int n = rest >> 3; int d = 8 + (rest & 7);
        kb[((size_t)bwh*NP + n)*16 + d] = 0;
        int d2 = 8 + rest / NP; int n2 = rest % NP;
        vtb[((size_t)bwh*16 + d2)*NP + n2] = (d2 == 8) ? (short)0x3F80 : (short)0;
    }
    if (i < NBWH*32) {
        int bwh = i >> 5; int rest = i & 31;
        int n = Nn + (rest >> 3); int d = rest & 7;
        qb[((size_t)bwh*NP + n)*8 + d] = 0;
        kb[((size_t)bwh*NP + n)*16 + d] = 0;
        int d3 = rest >> 2; int n3 = Nn + (rest & 3);
        vtb[((size_t)bwh*16 + d3)*NP + n3] = 0;
    }
}

// ---------------- QKV: register-column GEMM, 24 positions/block ----------------
__global__ __launch_bounds__(192) void qkv_kernel(const float* __restrict__ xin,
        const float* __restrict__ w, const float* __restrict__ bias,
        short* __restrict__ qb, short* __restrict__ kb, short* __restrict__ vtb) {
    __shared__ float xs[24][68];
    int tid = threadIdx.x;
    float wcol[64];
    #pragma unroll
    for (int c = 0; c < 64; ++c) wcol[c] = w[c*192 + tid];
    float bv = bias[tid];
    int p0 = blockIdx.x * 24;
    int b = p0 / TV;
    int r0 = p0 % TV;
    const float* xb = xin + (size_t)b*CTV;
    for (int i = tid; i < 24*64; i += 192) {
        int g = i % 24; int c = i / 24;
        xs[g][c] = xb[(size_t)c*TV + r0 + g];
    }
    __syncthreads();
    int which = tid >> 6; int cc = tid & 63;
    int h = cc >> 3; int d = cc & 7;
    for (int g = 0; g < 24; ++g) {
        float acc = bv;
        const float4* xv = (const float4*)xs[g];
        #pragma unroll
        for (int c4 = 0; c4 < 16; ++c4) {
            float4 x4 = xv[c4];
            acc += x4.x*wcol[c4*4+0] + x4.y*wcol[c4*4+1]
                 + x4.z*wcol[c4*4+2] + x4.w*wcol[c4*4+3];
        }
        int r = r0 + g;
        int t = r / Vv; int vv = r % Vv;
        int w_ = t >> 2; int tw = t & 3;
        int n = tw*Vv + vv;
        int bwh = (b*NW + w_)*Hh + h;
        if (which == 0)      qb[((size_t)bwh*NP + n)*8 + d] = f2bf(acc * QSCALE);
        else if (which == 1) kb[((size_t)bwh*NP + n)*16 + d] = f2bf(acc);
        else                 vtb[((size_t)bwh*16 + d)*NP + n] = f2bf(acc);
    }
}

// ---------------- Flash MFMA attention: 2 m-tiles/wave, prefetched ----------------
// grid = 256 bwh * 7 groups, 256 threads (4 waves x 2 m-tiles)
__global__ __launch_bounds__(256) void attn_kernel(const short* __restrict__ qb,
        const short* __restrict__ kb, const short* __restrict__ vtb,
        float* __restrict__ att) {
    int bwh = blockIdx.x / 7;
    int mtg = blockIdx.x % 7;
    int lane = threadIdx.x & 63;
    int wv = threadIdx.x >> 6;
    int quad = lane >> 4;
    int l15 = lane & 15;
    int mt0 = mtg*8 + wv*2;
    int mt1 = mt0 + 1;
    const short* qbase = qb + (size_t)bwh*NP*8;
    const short* kptr = kb + (size_t)bwh*NP*16 + l15*16 + quad*4;
    const short* vptr = vtb + (size_t)bwh*16*NP + l15*NP + quad*4;

    bf16x4 aq0 = {0,0,0,0}, aq1 = {0,0,0,0};
    if (quad < 2) {
        int m0 = (mt0 < 52) ? mt0 : 0;
        int m1 = (mt1 < 52) ? mt1 : 0;
        aq0 = *(const bf16x4*)(qbase + (m0*16 + l15)*8 + quad*4);
        aq1 = *(const bf16x4*)(qbase + (m1*16 + l15)*8 + quad*4);
    }

    f32x4 o0 = {0.f,0.f,0.f,0.f}, o1 = {0.f,0.f,0.f,0.f};
    bf16x4 ak = *(const bf16x4*)kptr;
    bf16x4 av = *(const bf16x4*)vptr;
    for (int nt = 0; nt < 52; ++nt) {
        bf16x4 akn = ak, avn = av;
        if (nt < 51) {
            akn = *(const bf16x4*)(kptr + (nt+1)*256);
            avn = *(const bf16x4*)(vptr + (nt+1)*16);
        }
        f32x4 s0 = __builtin_amdgcn_mfma_f32_16x16x16bf16_1k(
                       ak, aq0, (f32x4){0.f,0.f,0.f,0.f}, 0, 0, 0);
        f32x4 s1 = __builtin_amdgcn_mfma_f32_16x16x16bf16_1k(
                       ak, aq1, (f32x4){0.f,0.f,0.f,0.f}, 0, 0, 0);
        bf16x4 pb0 = pack4(__builtin_amdgcn_exp2f(s0[0]), __builtin_amdgcn_exp2f(s0[1]),
                           __builtin_amdgcn_exp2f(s0[2]), __builtin_amdgcn_exp2f(s0[3]));
        bf16x4 pb1 = pack4(__builtin_amdgcn_exp2f(s1[0]), __builtin_amdgcn_exp2f(s1[1]),
                           __builtin_amdgcn_exp2f(s1[2]), __builtin_amdgcn_exp2f(s1[3]));
        if (nt == 51 && quad == 3) {   // pad keys n=828..831 live exactly in quad 3
            pb0 = (bf16x4){0,0,0,0};
            pb1 = (bf16x4){0,0,0,0};
        }
        o0 = __builtin_amdgcn_mfma_f32_16x16x16bf16_1k(av, pb0, o0, 0, 0, 0);
        o1 = __builtin_amdgcn_mfma_f32_16x16x16bf16_1k(av, pb1, o1, 0, 0, 0);
        ak = akn; av = avn;
    }
    float ls0 = __shfl(o0[0], 32 + l15, 64);   // l-sum = O row 8
    float ls1 = __shfl(o1[0], 32 + l15, 64);
    float inv0 = 1.f / ls0;
    float inv1 = 1.f / ls1;
    int h = bwh & 7; int bw = bwh >> 3;
    if (quad < 2) {
        int m = mt0*16 + l15;
        if (m < Nn) {
            float* dst = att + ((size_t)bw*Nn + m)*Cc + h*DH + quad*4;
            dst[0] = o0[0]*inv0; dst[1] = o0[1]*inv0;
            dst[2] = o0[2]*inv0; dst[3] = o0[3]*inv0;
        }
        m = mt1*16 + l15;
        if (m < Nn) {
            float* dst = att + ((size_t)bw*Nn + m)*Cc + h*DH + quad*4;
            dst[0] = o1[0]*inv1; dst[1] = o1[1]*inv1;
            dst[2] = o1[2]*inv1; dst[3] = o1[3]*inv1;
        }
    }
}

// ---------------- Proj + residual + fused LN stats: 48 positions/block ----------------
// grid = 26496/48 = 552 blocks (48 | 3312 so one b per block), 256 threads
__global__ __launch_bounds__(256) void proj_kernel(const float* __restrict__ att,
        const float* __restrict__ wo, const float* __restrict__ bo,
        const float* __restrict__ resid, float* __restrict__ out,
        float* __restrict__ stats) {
    __shared__ float xs[48][68];
    __shared__ float r1[256], r2[256];
    int tid = threadIdx.x;
    int c = tid & 63; int wv = tid >> 6;
    float wcol[64];
    #pragma unroll
    for (int i = 0; i < 64; ++i) wcol[i] = wo[i*Cc + c];
    float bv = bo[c];
    int p0 = blockIdx.x * 48;
    int b = p0 / TV;
    int r0 = p0 % TV;
    for (int i = tid; i < 48*64; i += 256) {
        int g = i >> 6; int cc2 = i & 63;
        int r = r0 + g;
        int t = r / Vv; int vv = r % Vv;
        int w_ = t >> 2; int tw = t & 3;
        int n = tw*Vv + vv;
        int bw = b*NW + w_;
        xs[g][cc2] = att[((size_t)bw*Nn + n)*Cc + cc2];
    }
    __syncthreads();
    float s1 = 0.f, s2 = 0.f;
    for (int gi = 0; gi < 12; ++gi) {
        int g = wv*12 + gi;
        float acc = bv;
        const float4* xv = (const float4*)xs[g];
        #pragma unroll
        for (int c4 = 0; c4 < 16; ++c4) {
            float4 x4 = xv[c4];
            acc += x4.x*wcol[c4*4+0] + x4.y*wcol[c4*4+1]
                 + x4.z*wcol[c4*4+2] + x4.w*wcol[c4*4+3];
        }
        size_t oi = (size_t)b*CTV + (size_t)c*TV + (r0 + g);
        float val = acc + resid[oi];
        out[oi] = val;
        s1 += val; s2 += val*val;
    }
    r1[tid] = s1; r2[tid] = s2;
    __syncthreads();
    for (int o = 128; o > 0; o >>= 1) {
        if (tid < o) { r1[tid] += r1[tid+o]; r2[tid] += r2[tid+o]; }
        __syncthreads();
    }
    if (tid == 0) { atomicAdd(&stats[b*2], r1[0]); atomicAdd(&stats[b*2+1], r2[0]); }
}

// ---------------- LayerNorm apply (+roll via shift) ----------------
__global__ void ln_apply_kernel(const float* __restrict__ x,
                                const float* __restrict__ g,
                                const float* __restrict__ be,
                                const float* __restrict__ stats,
                                float* __restrict__ out,
                                int shift) {
    int idx = blockIdx.x*256 + threadIdx.x;
    if (idx >= S) return;
    int b = idx / CTV; int r = idx % CTV;
    int c = r / TV; int q2 = r % TV; int t = q2 / Vv; int vv = q2 % Vv;
    float mean = stats[b*2] * (1.0f/CTV);
    float var  = stats[b*2+1] * (1.0f/CTV) - mean*mean;
    float rstd = rsqrtf(var + EPSF);
    float val = (x[idx]-mean)*rstd*g[r] + be[r];
    int tout = (t - shift + Tt) % Tt;   // roll(-shift)
    size_t oidx = ((size_t)(b*Cc + c)*Tt + tout)*Vv + vv;
    out[oidx] = val;
}

// ---------------- FFN: MFMA two-stage + residual + fused LN stats ----------------
// grid = 8 b * 52 rblk = 416 blocks, 256 threads (4 waves x 16 positions; tail guarded)
__global__ __launch_bounds__(256) void ffn_kernel(const float* __restrict__ xin,
        const float* __restrict__ w1, const float* __restrict__ b1,
        const float* __restrict__ w2, const float* __restrict__ b2,
        float* __restrict__ out, float* __restrict__ stats) {
    __shared__ short w1s[4096*4];
    __shared__ short w2s[4096*4];
    __shared__ short xsf[1024*4];
    __shared__ float b1s[256];
    __shared__ float b2s[64];
    __shared__ float r1s[256], r2s[256];
    int tid = threadIdx.x;
    int b = blockIdx.x / 52;
    int r0 = (blockIdx.x % 52) * 64;
    const float* xb = xin + (size_t)b*CTV;

    for (int s2 = tid; s2 < 4096; s2 += 256) {
        int nt = s2 >> 8; int kc = (s2 >> 6) & 3; int ln = s2 & 63;
        int l15 = ln & 15; int quad = ln >> 4;
        bf16x4 f;
        #pragma unroll
        for (int j = 0; j < 4; ++j)
            f[j] = f2bf(w1[(kc*16 + quad*4 + j)*256 + nt*16 + l15]);
        *((bf16x4*)&w1s[s2*4]) = f;
    }
    for (int s2 = tid; s2 < 4096; s2 += 256) {
        int nt = s2 >> 8; int ct = (s2 >> 6) & 3; int ln = s2 & 63;
        int l15 = ln & 15; int quad = ln >> 4;
        bf16x4 f;
        #pragma unroll
        for (int j = 0; j < 4; ++j)
            f[j] = f2bf(w2[(nt*16 + quad*4 + j)*64 + ct*16 + l15]);
        *((bf16x4*)&w2s[s2*4]) = f;
    }
    for (int s2 = tid; s2 < 1024; s2 += 256) {
        int wv2 = s2 >> 8; int kc = (s2 >> 6) & 3; int ln = s2 & 63;
        int l15 = ln & 15; int quad = ln >> 4;
        int r = r0 + wv2*16 + l15; if (r >= TV) r = TV-1;
        bf16x4 f;
        #pragma unroll
        for (int j = 0; j < 4; ++j)
            f[j] = f2bf(xb[(size_t)(kc*16 + quad*4 + j)*TV + r]);
        *((bf16x4*)&xsf[s2*4]) = f;
    }
    b1s[tid] = b1[tid];
    if (tid < 64) b2s[tid] = b2[tid];
    __syncthreads();

    int lane = tid & 63; int wv = tid >> 6;
    int l15 = lane & 15; int quad = lane >> 4;
    bf16x4 xf[4];
    #pragma unroll
    for (int kc = 0; kc < 4; ++kc)
        xf[kc] = *((const bf16x4*)&xsf[((wv*4 + kc)*64 + lane)*4]);

    f32x4 oacc[4];
    #pragma unroll
    for (int ct = 0; ct < 4; ++ct) oacc[ct] = (f32x4){0.f,0.f,0.f,0.f};

    for (int nt = 0; nt < 16; ++nt) {
        float4 bb = *((const float4*)&b1s[nt*16 + quad*4]);
        f32x4 acc = {bb.x, bb.y, bb.z, bb.w};
        #pragma unroll
        for (int kc = 0; kc < 4; ++kc) {
            bf16x4 wf = *((const bf16x4*)&w1s[((nt*4 + kc)*64 + lane)*4]);
            acc = __builtin_amdgcn_mfma_f32_16x16x16bf16_1k(wf, xf[kc], acc, 0, 0, 0);
        }
        bf16x4 pf = pack4(fmaxf(acc[0], 0.f), fmaxf(acc[1], 0.f),
                          fmaxf(acc[2], 0.f), fmaxf(acc[3], 0.f));
        #pragma unroll
        for (int ct = 0; ct < 4; ++ct) {
            bf16x4 wf2 = *((const bf16x4*)&w2s[((nt*4 + ct)*64 + lane)*4]);
            oacc[ct] = __builtin_amdgcn_mfma_f32_16x16x16bf16_1k(wf2, pf, oacc[ct], 0, 0, 0);
        }
    }
    int r = r0 + wv*16 + l15;
    float s1 = 0.f, s2 = 0.f;
    if (r < TV) {
        #pragma unroll
        for (int ct = 0; ct < 4; ++ct) {
            #pragma unroll
            for (int j = 0; j < 4; ++j) {
                int c_out = ct*16 + quad*4 + j;
                size_t oi = (size_t)b*CTV + (size_t)c_out*TV + r;
                float val = oacc[ct][j] + b2s[c_out] + xb[(size_t)c_out*TV + r];
                out[oi] = val;
                s1 += val; s2 += val*val;
            }
        }
    }
    r1s[tid] = s1; r2s[tid] = s2;
    __syncthreads();
    for (int o = 128; o > 0; o >>= 1) {
        if (tid < o) { r1s[tid] += r1s[tid+o]; r2s[tid] += r2s[tid+o]; }
        __syncthreads();
    }
    if (tid == 0) { atomicAdd(&stats[b*2], r1s[0]); atomicAdd(&stats[b*2+1], r2s[0]); }
}

extern "C" void kernel_launch(void* const* d_in, const int* in_sizes, int n_in,
                              void* d_out, int out_size, void* d_ws, size_t ws_size,
                              hipStream_t stream) {
    const float* xin = (const float*)d_in[0];

    float* bufA  = (float*)d_ws;
    float* bufB  = bufA + S;
    float* att   = bufB + S;
    float* stats = att + S;          // 64 floats
    short* qb    = (short*)(stats + 64);            // [NBWH][NP][8]
    short* kb    = qb + (size_t)NBWH*NP*8;          // [NBWH][NP][16]
    short* vtb   = kb + (size_t)NBWH*NP*16;         // [NBWH][16][NP]

    prep_kernel<<<(NBWH*NP*8 + 255)/256, 256, 0, stream>>>(qb, kb, vtb, stats);

    for (int blk = 0; blk < 2; ++blk) {
        int o = 1 + blk*12;
        const float* qkvw = (const float*)d_in[o+0];
        const float* qkvb = (const float*)d_in[o+1];
        const float* pw   = (const float*)d_in[o+2];
        const float* pb   = (const float*)d_in[o+3];
        const float* fw1  = (const float*)d_in[o+4];
        const float* fb1  = (const float*)d_in[o+5];
        const float* fw2  = (const float*)d_in[o+6];
        const float* fb2  = (const float*)d_in[o+7];
        const float* g1   = (const float*)d_in[o+8];
        const float* be1  = (const float*)d_in[o+9];
        const float* g2   = (const float*)d_in[o+10];
        const float* be2  = (const float*)d_in[o+11];
        float* st1 = stats + blk*32;
        float* st2 = st1 + 16;

        const float* src = (blk == 0) ? xin : bufA;

        qkv_kernel<<<Bb*TV/24, 192, 0, stream>>>(src, qkvw, qkvb, qb, kb, vtb);
        attn_kernel<<<NBWH*7, 256, 0, stream>>>(qb, kb, vtb, att);
        proj_kernel<<<Bb*TV/48, 256, 0, stream>>>(att, pw, pb, src, bufB, st1);
        ln_apply_kernel<<<S/256, 256, 0, stream>>>(bufB, g1, be1, st1, bufA, 0);
        ffn_kernel<<<Bb*52, 256, 0, stream>>>(bufA, fw1, fb1, fw2, fb2, bufB, st2);
        bool fin = (blk == 1);
        ln_apply_kernel<<<S/256, 256, 0, stream>>>(bufB, g2, be2, st2,
                                                   fin ? (float*)d_out : bufA,
                                                   WSZ/2);
    }
}

// Round 6
// 399.968 us; speedup vs baseline: 2.5583x; 1.0241x over previous
//
#include <hip/hip_runtime.h>
#include <hip/hip_bf16.h>

#define Bb  8
#define Cc  64
#define Tt  16
#define Vv  207
#define Hh  8
#define DH  8
#define NW  4
#define WSZ 4
#define Nn  (WSZ*Vv)       // 828
#define NP  832            // padded window length (52*16)
#define TV  (Tt*Vv)        // 3312
#define CTV (Cc*Tt*Vv)     // 211968
#define S   (Bb*CTV)       // 1695744
#define NBWH (Bb*NW*Hh)    // 256
#define EPSF 1e-5f
// log2(e)/sqrt(8): folded into Q so softmax uses exp2 directly
#define QSCALE 0.51006971401146f

typedef __attribute__((ext_vector_type(4))) short bf16x4;
typedef __attribute__((ext_vector_type(4))) float f32x4;
typedef __attribute__((ext_vector_type(2))) unsigned int u32x2;

static __device__ __forceinline__ short f2bf(float f) {
    union { float f; unsigned u; } v; v.f = f;
    unsigned r = (v.u + 0x7FFFu + ((v.u >> 16) & 1u)) >> 16;  // RNE
    return (short)r;
}

// cheap pack: round-half-up (bias cancels in softmax; fine for ffn too)
static __device__ __forceinline__ bf16x4 pack4(float a, float b, float c, float d) {
    unsigned ua = __builtin_bit_cast(unsigned, a) + 0x8000u;
    unsigned ub = __builtin_bit_cast(unsigned, b) + 0x8000u;
    unsigned uc = __builtin_bit_cast(unsigned, c) + 0x8000u;
    unsigned ud = __builtin_bit_cast(unsigned, d) + 0x8000u;
    u32x2 t;
    t[0] = (ua >> 16) | (ub & 0xFFFF0000u);
    t[1] = (uc >> 16) | (ud & 0xFFFF0000u);
    return __builtin_bit_cast(bf16x4, t);
}

// ---------------- prep: zero stats, fill K/V pad regions ----------------
// kb layout [bwh][NP][16] (d=8..15 zero), vtb layout [bwh][16][NP]
// (row 8 = 1.0 for the l-sum trick), q/k/v n-pads zero.
__global__ void prep_kernel(short* __restrict__ qb, short* __restrict__ kb,
                            short* __restrict__ vtb, float* __restrict__ stats) {
    int i = blockIdx.x*256 + threadIdx.x;
    if (i < 64) stats[i] = 0.f;
    if (i < NBWH*NP*8) {
        int bwh = i / (NP*8); int rest = i % (NP*8);
        int n = rest >> 3; int d = 8 + (rest & 7);
        kb[((size_t)bwh*NP + n)*16 + d] = 0;
        int d2 = 8 + rest / NP; int n2 = rest % NP;
        vtb[((size_t)bwh*16 + d2)*NP + n2] = (d2 == 8) ? (short)0x3F80 : (short)0;
    }
    if (i < NBWH*32) {
        int bwh = i >> 5; int rest = i & 31;
        int n = Nn + (rest >> 3); int d = rest & 7;
        qb[((size_t)bwh*NP + n)*8 + d] = 0;
        kb[((size_t)bwh*NP + n)*16 + d] = 0;
        int d3 = rest >> 2; int n3 = Nn + (rest & 3);
        vtb[((size_t)bwh*16 + d3)*NP + n3] = 0;
    }
}

// ---------------- QKV: register-column GEMM, 24 positions/block ----------------
__global__ __launch_bounds__(192) void qkv_kernel(const float* __restrict__ xin,
        const float* __restrict__ w, const float* __restrict__ bias,
        short* __restrict__ qb, short* __restrict__ kb, short* __restrict__ vtb) {
    __shared__ float xs[24][68];
    int tid = threadIdx.x;
    float wcol[64];
    #pragma unroll
    for (int c = 0; c < 64; ++c) wcol[c] = w[c*192 + tid];
    float bv = bias[tid];
    int p0 = blockIdx.x * 24;
    int b = p0 / TV;
    int r0 = p0 % TV;
    const float* xb = xin + (size_t)b*CTV;
    for (int i = tid; i < 24*64; i += 192) {
        int g = i % 24; int c = i / 24;
        xs[g][c] = xb[(size_t)c*TV + r0 + g];
    }
    __syncthreads();
    int which = tid >> 6; int cc = tid & 63;
    int h = cc >> 3; int d = cc & 7;
    for (int g = 0; g < 24; ++g) {
        float acc = bv;
        const float4* xv = (const float4*)xs[g];
        #pragma unroll
        for (int c4 = 0; c4 < 16; ++c4) {
            float4 x4 = xv[c4];
            acc += x4.x*wcol[c4*4+0] + x4.y*wcol[c4*4+1]
                 + x4.z*wcol[c4*4+2] + x4.w*wcol[c4*4+3];
        }
        int r = r0 + g;
        int t = r / Vv; int vv = r % Vv;
        int w_ = t >> 2; int tw = t & 3;
        int n = tw*Vv + vv;
        int bwh = (b*NW + w_)*Hh + h;
        if (which == 0)      qb[((size_t)bwh*NP + n)*8 + d] = f2bf(acc * QSCALE);
        else if (which == 1) kb[((size_t)bwh*NP + n)*16 + d] = f2bf(acc);
        else                 vtb[((size_t)bwh*16 + d)*NP + n] = f2bf(acc);
    }
}

// ---------------- Flash MFMA attention: one block per bwh, K/V in LDS ----------------
// grid = 256 blocks, 256 threads (4 waves x 13 m-tiles each)
__global__ __launch_bounds__(256) void attn_kernel(const short* __restrict__ qb,
        const short* __restrict__ kb, const short* __restrict__ vtb,
        float* __restrict__ att) {
    __shared__ short ks[NP*20];     // K rows, stride 20 (16 data + 4 pad), 33.3 KB
    __shared__ short vs[10*840];    // V^T rows 0..8 + zero row 9, stride 840, 16.8 KB
    int bwh = blockIdx.x;
    int tid = threadIdx.x;
    int lane = tid & 63;
    int wv = tid >> 6;
    int quad = lane >> 4;
    int l15 = lane & 15;

    // stage K: global [NP][16] -> LDS [NP][20] (coalesced uint2)
    const u32x2* kg = (const u32x2*)(kb + (size_t)bwh*NP*16);
    for (int idx = tid; idx < NP*4; idx += 256) {
        int n = idx >> 2; int j = idx & 3;
        *((u32x2*)&ks[n*20 + j*4]) = kg[idx];
    }
    // stage V^T rows 0..8; row 9 zeros
    const u32x2* vg = (const u32x2*)(vtb + (size_t)bwh*16*NP);
    for (int idx = tid; idx < 9*208; idx += 256) {
        int rr = idx / 208; int j = idx % 208;
        *((u32x2*)&vs[rr*840 + j*4]) = vg[rr*208 + j];
    }
    if (tid < 210) *((u32x2*)&vs[9*840 + tid*4]) = (u32x2){0u, 0u};
    __syncthreads();

    const short* qbase = qb + (size_t)bwh*NP*8;
    bf16x4 aq[13];
    #pragma unroll
    for (int i = 0; i < 13; ++i) {
        int mt = wv + 4*i;
        aq[i] = (bf16x4){0,0,0,0};
        if (quad < 2)
            aq[i] = *(const bf16x4*)(qbase + ((mt*16 + l15)*8 + quad*4));
    }
    f32x4 oacc[13];
    #pragma unroll
    for (int i = 0; i < 13; ++i) oacc[i] = (f32x4){0.f,0.f,0.f,0.f};

    const short* kls = &ks[l15*20 + quad*4];
    const short* vls = &vs[((l15 < 9) ? l15 : 9)*840 + quad*4];

    for (int nt = 0; nt < 52; ++nt) {
        bf16x4 ak = *(const bf16x4*)(kls + nt*320);
        bf16x4 av = *(const bf16x4*)(vls + nt*16);
        bool mask = (nt == 51) && (quad == 3);   // pad keys n=828..831
        #pragma unroll
        for (int i = 0; i < 13; ++i) {
            f32x4 s = __builtin_amdgcn_mfma_f32_16x16x16bf16_1k(
                          ak, aq[i], (f32x4){0.f,0.f,0.f,0.f}, 0, 0, 0);
            bf16x4 pb = pack4(__builtin_amdgcn_exp2f(s[0]), __builtin_amdgcn_exp2f(s[1]),
                              __builtin_amdgcn_exp2f(s[2]), __builtin_amdgcn_exp2f(s[3]));
            if (mask) pb = (bf16x4){0,0,0,0};
            oacc[i] = __builtin_amdgcn_mfma_f32_16x16x16bf16_1k(av, pb, oacc[i], 0, 0, 0);
        }
    }
    int h = bwh & 7; int bw = bwh >> 3;
    #pragma unroll
    for (int i = 0; i < 13; ++i) {
        float ls = __shfl(oacc[i][0], 32 + l15, 64);   // l-sum = O row 8
        float inv = 1.f / ls;
        int m = (wv + 4*i)*16 + l15;
        if (quad < 2 && m < Nn) {
            float* dst = att + ((size_t)bw*Nn + m)*Cc + h*DH + quad*4;
            dst[0] = oacc[i][0]*inv; dst[1] = oacc[i][1]*inv;
            dst[2] = oacc[i][2]*inv; dst[3] = oacc[i][3]*inv;
        }
    }
}

// ---------------- Proj + residual + fused LN stats: 48 positions/block ----------------
__global__ __launch_bounds__(256) void proj_kernel(const float* __restrict__ att,
        const float* __restrict__ wo, const float* __restrict__ bo,
        const float* __restrict__ resid, float* __restrict__ out,
        float* __restrict__ stats) {
    __shared__ float xs[48][68];
    __shared__ float r1[256], r2[256];
    int tid = threadIdx.x;
    int c = tid & 63; int wv = tid >> 6;
    float wcol[64];
    #pragma unroll
    for (int i = 0; i < 64; ++i) wcol[i] = wo[i*Cc + c];
    float bv = bo[c];
    int p0 = blockIdx.x * 48;
    int b = p0 / TV;
    int r0 = p0 % TV;
    for (int i = tid; i < 48*64; i += 256) {
        int g = i >> 6; int cc2 = i & 63;
        int r = r0 + g;
        int t = r / Vv; int vv = r % Vv;
        int w_ = t >> 2; int tw = t & 3;
        int n = tw*Vv + vv;
        int bw = b*NW + w_;
        xs[g][cc2] = att[((size_t)bw*Nn + n)*Cc + cc2];
    }
    __syncthreads();
    float s1 = 0.f, s2 = 0.f;
    for (int gi = 0; gi < 12; ++gi) {
        int g = wv*12 + gi;
        float acc = bv;
        const float4* xv = (const float4*)xs[g];
        #pragma unroll
        for (int c4 = 0; c4 < 16; ++c4) {
            float4 x4 = xv[c4];
            acc += x4.x*wcol[c4*4+0] + x4.y*wcol[c4*4+1]
                 + x4.z*wcol[c4*4+2] + x4.w*wcol[c4*4+3];
        }
        size_t oi = (size_t)b*CTV + (size_t)c*TV + (r0 + g);
        float val = acc + resid[oi];
        out[oi] = val;
        s1 += val; s2 += val*val;
    }
    r1[tid] = s1; r2[tid] = s2;
    __syncthreads();
    for (int o = 128; o > 0; o >>= 1) {
        if (tid < o) { r1[tid] += r1[tid+o]; r2[tid] += r2[tid+o]; }
        __syncthreads();
    }
    if (tid == 0) { atomicAdd(&stats[b*2], r1[0]); atomicAdd(&stats[b*2+1], r2[0]); }
}

// ---------------- LayerNorm apply (+roll via shift) ----------------
__global__ void ln_apply_kernel(const float* __restrict__ x,
                                const float* __restrict__ g,
                                const float* __restrict__ be,
                                const float* __restrict__ stats,
                                float* __restrict__ out,
                                int shift) {
    int idx = blockIdx.x*256 + threadIdx.x;
    if (idx >= S) return;
    int b = idx / CTV; int r = idx % CTV;
    int c = r / TV; int q2 = r % TV; int t = q2 / Vv; int vv = q2 % Vv;
    float mean = stats[b*2] * (1.0f/CTV);
    float var  = stats[b*2+1] * (1.0f/CTV) - mean*mean;
    float rstd = rsqrtf(var + EPSF);
    float val = (x[idx]-mean)*rstd*g[r] + be[r];
    int tout = (t - shift + Tt) % Tt;   // roll(-shift)
    size_t oidx = ((size_t)(b*Cc + c)*Tt + tout)*Vv + vv;
    out[oidx] = val;
}

// ---------------- FFN: MFMA two-stage + residual + fused LN stats ----------------
__global__ __launch_bounds__(256) void ffn_kernel(const float* __restrict__ xin,
        const float* __restrict__ w1, const float* __restrict__ b1,
        const float* __restrict__ w2, const float* __restrict__ b2,
        float* __restrict__ out, float* __restrict__ stats) {
    __shared__ short w1s[4096*4];
    __shared__ short w2s[4096*4];
    __shared__ short xsf[1024*4];
    __shared__ float b1s[256];
    __shared__ float b2s[64];
    __shared__ float r1s[256], r2s[256];
    int tid = threadIdx.x;
    int b = blockIdx.x / 52;
    int r0 = (blockIdx.x % 52) * 64;
    const float* xb = xin + (size_t)b*CTV;

    for (int s2 = tid; s2 < 4096; s2 += 256) {
        int nt = s2 >> 8; int kc = (s2 >> 6) & 3; int ln = s2 & 63;
        int l15 = ln & 15; int quad = ln >> 4;
        bf16x4 f;
        #pragma unroll
        for (int j = 0; j < 4; ++j)
            f[j] = f2bf(w1[(kc*16 + quad*4 + j)*256 + nt*16 + l15]);
        *((bf16x4*)&w1s[s2*4]) = f;
    }
    for (int s2 = tid; s2 < 4096; s2 += 256) {
        int nt = s2 >> 8; int ct = (s2 >> 6) & 3; int ln = s2 & 63;
        int l15 = ln & 15; int quad = ln >> 4;
        bf16x4 f;
        #pragma unroll
        for (int j = 0; j < 4; ++j)
            f[j] = f2bf(w2[(nt*16 + quad*4 + j)*64 + ct*16 + l15]);
        *((bf16x4*)&w2s[s2*4]) = f;
    }
    for (int s2 = tid; s2 < 1024; s2 += 256) {
        int wv2 = s2 >> 8; int kc = (s2 >> 6) & 3; int ln = s2 & 63;
        int l15 = ln & 15; int quad = ln >> 4;
        int r = r0 + wv2*16 + l15; if (r >= TV) r = TV-1;
        bf16x4 f;
        #pragma unroll
        for (int j = 0; j < 4; ++j)
            f[j] = f2bf(xb[(size_t)(kc*16 + quad*4 + j)*TV + r]);
        *((bf16x4*)&xsf[s2*4]) = f;
    }
    b1s[tid] = b1[tid];
    if (tid < 64) b2s[tid] = b2[tid];
    __syncthreads();

    int lane = tid & 63; int wv = tid >> 6;
    int l15 = lane & 15; int quad = lane >> 4;
    bf16x4 xf[4];
    #pragma unroll
    for (int kc = 0; kc < 4; ++kc)
        xf[kc] = *((const bf16x4*)&xsf[((wv*4 + kc)*64 + lane)*4]);

    f32x4 oacc[4];
    #pragma unroll
    for (int ct = 0; ct < 4; ++ct) oacc[ct] = (f32x4){0.f,0.f,0.f,0.f};

    for (int nt = 0; nt < 16; ++nt) {
        float4 bb = *((const float4*)&b1s[nt*16 + quad*4]);
        f32x4 acc = {bb.x, bb.y, bb.z, bb.w};
        #pragma unroll
        for (int kc = 0; kc < 4; ++kc) {
            bf16x4 wf = *((const bf16x4*)&w1s[((nt*4 + kc)*64 + lane)*4]);
            acc = __builtin_amdgcn_mfma_f32_16x16x16bf16_1k(wf, xf[kc], acc, 0, 0, 0);
        }
        bf16x4 pf = pack4(fmaxf(acc[0], 0.f), fmaxf(acc[1], 0.f),
                          fmaxf(acc[2], 0.f), fmaxf(acc[3], 0.f));
        #pragma unroll
        for (int ct = 0; ct < 4; ++ct) {
            bf16x4 wf2 = *((const bf16x4*)&w2s[((nt*4 + ct)*64 + lane)*4]);
            oacc[ct] = __builtin_amdgcn_mfma_f32_16x16x16bf16_1k(wf2, pf, oacc[ct], 0, 0, 0);
        }
    }
    int r = r0 + wv*16 + l15;
    float s1 = 0.f, s2 = 0.f;
    if (r < TV) {
        #pragma unroll
        for (int ct = 0; ct < 4; ++ct) {
            #pragma unroll
            for (int j = 0; j < 4; ++j) {
                int c_out = ct*16 + quad*4 + j;
                size_t oi = (size_t)b*CTV + (size_t)c_out*TV + r;
                float val = oacc[ct][j] + b2s[c_out] + xb[(size_t)c_out*TV + r];
                out[oi] = val;
                s1 += val; s2 += val*val;
            }
        }
    }
    r1s[tid] = s1; r2s[tid] = s2;
    __syncthreads();
    for (int o = 128; o > 0; o >>= 1) {
        if (tid < o) { r1s[tid] += r1s[tid+o]; r2s[tid] += r2s[tid+o]; }
        __syncthreads();
    }
    if (tid == 0) { atomicAdd(&stats[b*2], r1s[0]); atomicAdd(&stats[b*2+1], r2s[0]); }
}

extern "C" void kernel_launch(void* const* d_in, const int* in_sizes, int n_in,
                              void* d_out, int out_size, void* d_ws, size_t ws_size,
                              hipStream_t stream) {
    const float* xin = (const float*)d_in[0];

    float* bufA  = (float*)d_ws;
    float* bufB  = bufA + S;
    float* att   = bufB + S;
    float* stats = att + S;          // 64 floats
    short* qb    = (short*)(stats + 64);            // [NBWH][NP][8]
    short* kb    = qb + (size_t)NBWH*NP*8;          // [NBWH][NP][16]
    short* vtb   = kb + (size_t)NBWH*NP*16;         // [NBWH][16][NP]

    prep_kernel<<<(NBWH*NP*8 + 255)/256, 256, 0, stream>>>(qb, kb, vtb, stats);

    for (int blk = 0; blk < 2; ++blk) {
        int o = 1 + blk*12;
        const float* qkvw = (const float*)d_in[o+0];
        const float* qkvb = (const float*)d_in[o+1];
        const float* pw   = (const float*)d_in[o+2];
        const float* pb   = (const float*)d_in[o+3];
        const float* fw1  = (const float*)d_in[o+4];
        const float* fb1  = (const float*)d_in[o+5];
        const float* fw2  = (const float*)d_in[o+6];
        const float* fb2  = (const float*)d_in[o+7];
        const float* g1   = (const float*)d_in[o+8];
        const float* be1  = (const float*)d_in[o+9];
        const float* g2   = (const float*)d_in[o+10];
        const float* be2  = (const float*)d_in[o+11];
        float* st1 = stats + blk*32;
        float* st2 = st1 + 16;

        const float* src = (blk == 0) ? xin : bufA;

        qkv_kernel<<<Bb*TV/24, 192, 0, stream>>>(src, qkvw, qkvb, qb, kb, vtb);
        attn_kernel<<<NBWH, 256, 0, stream>>>(qb, kb, vtb, att);
        proj_kernel<<<Bb*TV/48, 256, 0, stream>>>(att, pw, pb, src, bufB, st1);
        ln_apply_kernel<<<S/256, 256, 0, stream>>>(bufB, g1, be1, st1, bufA, 0);
        ffn_kernel<<<Bb*52, 256, 0, stream>>>(bufA, fw1, fb1, fw2, fb2, bufB, st2);
        bool fin = (blk == 1);
        ln_apply_kernel<<<S/256, 256, 0, stream>>>(bufB, g2, be2, st2,
                                                   fin ? (float*)d_out : bufA,
                                                   WSZ/2);
    }
}

// Round 7
// 305.993 us; speedup vs baseline: 3.3440x; 1.3071x over previous
//
#include <hip/hip_runtime.h>
#include <hip/hip_bf16.h>

#define Bb  8
#define Cc  64
#define Tt  16
#define Vv  207
#define Hh  8
#define DH  8
#define NW  4
#define WSZ 4
#define Nn  (WSZ*Vv)       // 828
#define NP  832            // padded window length (52*16)
#define TV  (Tt*Vv)        // 3312
#define CTV (Cc*Tt*Vv)     // 211968
#define S   (Bb*CTV)       // 1695744
#define NBWH (Bb*NW*Hh)    // 256
#define EPSF 1e-5f
// log2(e)/sqrt(8): folded into Q so softmax uses exp2 directly
#define QSCALE 0.51006971401146f

typedef __attribute__((ext_vector_type(4))) short bf16x4;
typedef __attribute__((ext_vector_type(4))) float f32x4;
typedef __attribute__((ext_vector_type(2))) unsigned int u32x2;

static __device__ __forceinline__ short f2bf(float f) {
    union { float f; unsigned u; } v; v.f = f;
    unsigned r = (v.u + 0x7FFFu + ((v.u >> 16) & 1u)) >> 16;  // RNE
    return (short)r;
}

// cheap pack: round-half-up (bias cancels in softmax; fine elsewhere too)
static __device__ __forceinline__ bf16x4 pack4(float a, float b, float c, float d) {
    unsigned ua = __builtin_bit_cast(unsigned, a) + 0x8000u;
    unsigned ub = __builtin_bit_cast(unsigned, b) + 0x8000u;
    unsigned uc = __builtin_bit_cast(unsigned, c) + 0x8000u;
    unsigned ud = __builtin_bit_cast(unsigned, d) + 0x8000u;
    u32x2 t;
    t[0] = (ua >> 16) | (ub & 0xFFFF0000u);
    t[1] = (uc >> 16) | (ud & 0xFFFF0000u);
    return __builtin_bit_cast(bf16x4, t);
}

// ---------------- prep: zero stats, fill K/V pad regions ----------------
__global__ void prep_kernel(short* __restrict__ qb, short* __restrict__ kb,
                            short* __restrict__ vtb, float* __restrict__ stats) {
    int i = blockIdx.x*256 + threadIdx.x;
    if (i < 64) stats[i] = 0.f;
    if (i < NBWH*NP*8) {
        int bwh = i / (NP*8); int rest = i % (NP*8);
        int n = rest >> 3; int d = 8 + (rest & 7);
        kb[((size_t)bwh*NP + n)*16 + d] = 0;
        int d2 = 8 + rest / NP; int n2 = rest % NP;
        vtb[((size_t)bwh*16 + d2)*NP + n2] = (d2 == 8) ? (short)0x3F80 : (short)0;
    }
    if (i < NBWH*32) {
        int bwh = i >> 5; int rest = i & 31;
        int n = Nn + (rest >> 3); int d = rest & 7;
        qb[((size_t)bwh*NP + n)*8 + d] = 0;
        kb[((size_t)bwh*NP + n)*16 + d] = 0;
        int d3 = rest >> 2; int n3 = Nn + (rest & 3);
        vtb[((size_t)bwh*16 + d3)*NP + n3] = 0;
    }
}

// ---------------- QKV: MFMA GEMM [64pos x 64] @ [64 x 192] ----------------
// grid = 8 b * 52 tiles = 416 blocks, 256 threads (4 waves x 16 positions)
__global__ __launch_bounds__(256) void qkv_kernel(const float* __restrict__ xin,
        const float* __restrict__ w, const float* __restrict__ bias,
        short* __restrict__ qb, short* __restrict__ kb, short* __restrict__ vtb) {
    __shared__ short wqs[3072*4];   // 24 KB: [nt(12)][kc(4)][lane] bf16x4 frags
    __shared__ float bqs[192];
    int tid = threadIdx.x;
    int b = blockIdx.x / 52;
    int r0 = (blockIdx.x % 52) * 64;
    const float* xb = xin + (size_t)b*CTV;
    for (int s = tid; s < 3072; s += 256) {
        int nt = s >> 8; int kc = (s >> 6) & 3; int ln = s & 63;
        int li = ln & 15; int q = ln >> 4;
        bf16x4 f;
        #pragma unroll
        for (int j = 0; j < 4; ++j)
            f[j] = f2bf(w[(kc*16 + q*4 + j)*192 + nt*16 + li]);
        *((bf16x4*)&wqs[s*4]) = f;
    }
    if (tid < 192) bqs[tid] = bias[tid];
    __syncthreads();

    int lane = tid & 63; int wv = tid >> 6;
    int l15 = lane & 15; int quad = lane >> 4;
    int r = r0 + wv*16 + l15;
    bool valid = r < TV;
    int rc = valid ? r : TV-1;
    bf16x4 xf[4];
    #pragma unroll
    for (int kc = 0; kc < 4; ++kc) {
        #pragma unroll
        for (int j = 0; j < 4; ++j)
            xf[kc][j] = f2bf(xb[(size_t)(kc*16 + quad*4 + j)*TV + rc]);
    }
    int t = rc / Vv; int vv = rc % Vv;
    int w_ = t >> 2; int tw = t & 3;
    int n = tw*Vv + vv;
    int bwbase = (b*NW + w_)*Hh;

    #pragma unroll
    for (int nt = 0; nt < 12; ++nt) {
        float4 bb = *((const float4*)&bqs[nt*16 + quad*4]);
        f32x4 acc = {bb.x, bb.y, bb.z, bb.w};
        #pragma unroll
        for (int kc = 0; kc < 4; ++kc) {
            bf16x4 wf = *((const bf16x4*)&wqs[((nt*4 + kc)*64 + lane)*4]);
            acc = __builtin_amdgcn_mfma_f32_16x16x16bf16_1k(wf, xf[kc], acc, 0, 0, 0);
        }
        if (valid) {
            int which = nt >> 2;           // wave-uniform
            #pragma unroll
            for (int j = 0; j < 4; ++j) {
                int cc = (nt & 3)*16 + quad*4 + j;
                int h = cc >> 3; int d = cc & 7;
                int bwh = bwbase + h;
                if (which == 0)      qb[((size_t)bwh*NP + n)*8 + d] = f2bf(acc[j]*QSCALE);
                else if (which == 1) kb[((size_t)bwh*NP + n)*16 + d] = f2bf(acc[j]);
                else                 vtb[((size_t)bwh*16 + d)*NP + n] = f2bf(acc[j]);
            }
        }
    }
}

// ---------------- Flash MFMA attention: 1024 threads/block, K/V in LDS ----------------
// grid = 256 blocks, 16 waves: wave wv owns m-tiles wv+16*i (4 tiles for wv<4, else 3)
__global__ __launch_bounds__(1024) void attn_kernel(const short* __restrict__ qb,
        const short* __restrict__ kb, const short* __restrict__ vtb,
        short* __restrict__ att) {
    __shared__ short ks[NP*20];     // K rows, stride 20, 33.3 KB
    __shared__ short vs[10*840];    // V^T rows 0..8 + zero row 9, 16.8 KB
    int bwh = blockIdx.x;
    int tid = threadIdx.x;
    int lane = tid & 63;
    int wv = tid >> 6;              // 0..15
    int quad = lane >> 4;
    int l15 = lane & 15;

    const u32x2* kg = (const u32x2*)(kb + (size_t)bwh*NP*16);
    for (int idx = tid; idx < NP*4; idx += 1024) {
        int n = idx >> 2; int j = idx & 3;
        *((u32x2*)&ks[n*20 + j*4]) = kg[idx];
    }
    const u32x2* vg = (const u32x2*)(vtb + (size_t)bwh*16*NP);
    for (int idx = tid; idx < 9*208; idx += 1024) {
        int rr = idx / 208; int j = idx % 208;
        *((u32x2*)&vs[rr*840 + j*4]) = vg[rr*208 + j];
    }
    if (tid < 210) *((u32x2*)&vs[9*840 + tid*4]) = (u32x2){0u, 0u};
    __syncthreads();

    int nm = (wv < 4) ? 4 : 3;
    const short* qbase = qb + (size_t)bwh*NP*8;
    bf16x4 aq[4];
    f32x4 oacc[4];
    #pragma unroll
    for (int i = 0; i < 4; ++i) {
        aq[i] = (bf16x4){0,0,0,0};
        oacc[i] = (f32x4){0.f,0.f,0.f,0.f};
        if (i < nm && quad < 2)
            aq[i] = *(const bf16x4*)(qbase + (((wv + 16*i)*16 + l15)*8 + quad*4));
    }
    const short* kls = &ks[l15*20 + quad*4];
    const short* vls = &vs[((l15 < 9) ? l15 : 9)*840 + quad*4];

    for (int nt = 0; nt < 52; ++nt) {
        bf16x4 ak = *(const bf16x4*)(kls + nt*320);
        bf16x4 av = *(const bf16x4*)(vls + nt*16);
        bool mask = (nt == 51) && (quad == 3);   // pad keys n=828..831
        #pragma unroll
        for (int i = 0; i < 4; ++i) {
            if (i < nm) {
                f32x4 s = __builtin_amdgcn_mfma_f32_16x16x16bf16_1k(
                              ak, aq[i], (f32x4){0.f,0.f,0.f,0.f}, 0, 0, 0);
                bf16x4 pb = pack4(__builtin_amdgcn_exp2f(s[0]), __builtin_amdgcn_exp2f(s[1]),
                                  __builtin_amdgcn_exp2f(s[2]), __builtin_amdgcn_exp2f(s[3]));
                if (mask) pb = (bf16x4){0,0,0,0};
                oacc[i] = __builtin_amdgcn_mfma_f32_16x16x16bf16_1k(av, pb, oacc[i], 0, 0, 0);
            }
        }
    }
    int h = bwh & 7; int bw = bwh >> 3;
    #pragma unroll
    for (int i = 0; i < 4; ++i) {
        if (i < nm) {
            float ls = __shfl(oacc[i][0], 32 + l15, 64);   // l-sum = O row 8
            float inv = 1.f / ls;
            int m = (wv + 16*i)*16 + l15;
            if (quad < 2 && m < Nn) {
                bf16x4 ov = pack4(oacc[i][0]*inv, oacc[i][1]*inv,
                                  oacc[i][2]*inv, oacc[i][3]*inv);
                *((bf16x4*)&att[((size_t)bw*Nn + m)*Cc + h*DH + quad*4]) = ov;
            }
        }
    }
}

// ---------------- Proj: MFMA [64pos x 64] @ [64 x 64] + residual + LN stats ----------------
// grid = 416 blocks, 256 threads; att frags loaded directly (already B-op layout)
__global__ __launch_bounds__(256) void proj_kernel(const short* __restrict__ att,
        const float* __restrict__ wo, const float* __restrict__ bo,
        const float* __restrict__ resid, float* __restrict__ out,
        float* __restrict__ stats) {
    __shared__ short wos[1024*4];   // 8 KB: [nt(4)][kc(4)][lane]
    __shared__ float bos[64];
    __shared__ float r1[256], r2[256];
    int tid = threadIdx.x;
    int b = blockIdx.x / 52;
    int r0 = (blockIdx.x % 52) * 64;
    const float* xb = resid + (size_t)b*CTV;
    for (int s = tid; s < 1024; s += 256) {
        int nt = s >> 8; int kc = (s >> 6) & 3; int ln = s & 63;
        int li = ln & 15; int q = ln >> 4;
        bf16x4 f;
        #pragma unroll
        for (int j = 0; j < 4; ++j)
            f[j] = f2bf(wo[(kc*16 + q*4 + j)*64 + nt*16 + li]);
        *((bf16x4*)&wos[s*4]) = f;
    }
    if (tid < 64) bos[tid] = bo[tid];
    __syncthreads();

    int lane = tid & 63; int wv = tid >> 6;
    int l15 = lane & 15; int quad = lane >> 4;
    int r = r0 + wv*16 + l15;
    bool valid = r < TV;
    int rc = valid ? r : TV-1;
    int t = rc / Vv; int vv = rc % Vv;
    int w_ = t >> 2; int tw = t & 3;
    int n = tw*Vv + vv;
    int bw = b*NW + w_;
    const short* arow = att + ((size_t)bw*Nn + n)*Cc;
    bf16x4 af[4];
    #pragma unroll
    for (int kc = 0; kc < 4; ++kc)
        af[kc] = *((const bf16x4*)&arow[kc*16 + quad*4]);

    f32x4 acc[4];
    #pragma unroll
    for (int nt = 0; nt < 4; ++nt) {
        float4 bb = *((const float4*)&bos[nt*16 + quad*4]);
        acc[nt] = (f32x4){bb.x, bb.y, bb.z, bb.w};
        #pragma unroll
        for (int kc = 0; kc < 4; ++kc) {
            bf16x4 wf = *((const bf16x4*)&wos[((nt*4 + kc)*64 + lane)*4]);
            acc[nt] = __builtin_amdgcn_mfma_f32_16x16x16bf16_1k(wf, af[kc], acc[nt], 0, 0, 0);
        }
    }
    float s1 = 0.f, s2 = 0.f;
    if (valid) {
        #pragma unroll
        for (int nt = 0; nt < 4; ++nt) {
            #pragma unroll
            for (int j = 0; j < 4; ++j) {
                int c_out = nt*16 + quad*4 + j;
                size_t oi = (size_t)b*CTV + (size_t)c_out*TV + r;
                float val = acc[nt][j] + xb[(size_t)c_out*TV + r];
                out[oi] = val;
                s1 += val; s2 += val*val;
            }
        }
    }
    r1[tid] = s1; r2[tid] = s2;
    __syncthreads();
    for (int o = 128; o > 0; o >>= 1) {
        if (tid < o) { r1[tid] += r1[tid+o]; r2[tid] += r2[tid+o]; }
        __syncthreads();
    }
    if (tid == 0) { atomicAdd(&stats[b*2], r1[0]); atomicAdd(&stats[b*2+1], r2[0]); }
}

// ---------------- LayerNorm apply (+roll via shift) ----------------
__global__ void ln_apply_kernel(const float* __restrict__ x,
                                const float* __restrict__ g,
                                const float* __restrict__ be,
                                const float* __restrict__ stats,
                                float* __restrict__ out,
                                int shift) {
    int idx = blockIdx.x*256 + threadIdx.x;
    if (idx >= S) return;
    int b = idx / CTV; int r = idx % CTV;
    int c = r / TV; int q2 = r % TV; int t = q2 / Vv; int vv = q2 % Vv;
    float mean = stats[b*2] * (1.0f/CTV);
    float var  = stats[b*2+1] * (1.0f/CTV) - mean*mean;
    float rstd = rsqrtf(var + EPSF);
    float val = (x[idx]-mean)*rstd*g[r] + be[r];
    int tout = (t - shift + Tt) % Tt;   // roll(-shift)
    size_t oidx = ((size_t)(b*Cc + c)*Tt + tout)*Vv + vv;
    out[oidx] = val;
}

// ---------------- FFN: MFMA two-stage + residual + fused LN stats ----------------
__global__ __launch_bounds__(256) void ffn_kernel(const float* __restrict__ xin,
        const float* __restrict__ w1, const float* __restrict__ b1,
        const float* __restrict__ w2, const float* __restrict__ b2,
        float* __restrict__ out, float* __restrict__ stats) {
    __shared__ short w1s[4096*4];
    __shared__ short w2s[4096*4];
    __shared__ short xsf[1024*4];
    __shared__ float b1s[256];
    __shared__ float b2s[64];
    __shared__ float r1s[256], r2s[256];
    int tid = threadIdx.x;
    int b = blockIdx.x / 52;
    int r0 = (blockIdx.x % 52) * 64;
    const float* xb = xin + (size_t)b*CTV;

    for (int s2 = tid; s2 < 4096; s2 += 256) {
        int nt = s2 >> 8; int kc = (s2 >> 6) & 3; int ln = s2 & 63;
        int l15 = ln & 15; int quad = ln >> 4;
        bf16x4 f;
        #pragma unroll
        for (int j = 0; j < 4; ++j)
            f[j] = f2bf(w1[(kc*16 + quad*4 + j)*256 + nt*16 + l15]);
        *((bf16x4*)&w1s[s2*4]) = f;
    }
    for (int s2 = tid; s2 < 4096; s2 += 256) {
        int nt = s2 >> 8; int ct = (s2 >> 6) & 3; int ln = s2 & 63;
        int l15 = ln & 15; int quad = ln >> 4;
        bf16x4 f;
        #pragma unroll
        for (int j = 0; j < 4; ++j)
            f[j] = f2bf(w2[(nt*16 + quad*4 + j)*64 + ct*16 + l15]);
        *((bf16x4*)&w2s[s2*4]) = f;
    }
    for (int s2 = tid; s2 < 1024; s2 += 256) {
        int wv2 = s2 >> 8; int kc = (s2 >> 6) & 3; int ln = s2 & 63;
        int l15 = ln & 15; int quad = ln >> 4;
        int r = r0 + wv2*16 + l15; if (r >= TV) r = TV-1;
        bf16x4 f;
        #pragma unroll
        for (int j = 0; j < 4; ++j)
            f[j] = f2bf(xb[(size_t)(kc*16 + quad*4 + j)*TV + r]);
        *((bf16x4*)&xsf[s2*4]) = f;
    }
    b1s[tid] = b1[tid];
    if (tid < 64) b2s[tid] = b2[tid];
    __syncthreads();

    int lane = tid & 63; int wv = tid >> 6;
    int l15 = lane & 15; int quad = lane >> 4;
    bf16x4 xf[4];
    #pragma unroll
    for (int kc = 0; kc < 4; ++kc)
        xf[kc] = *((const bf16x4*)&xsf[((wv*4 + kc)*64 + lane)*4]);

    f32x4 oacc[4];
    #pragma unroll
    for (int ct = 0; ct < 4; ++ct) oacc[ct] = (f32x4){0.f,0.f,0.f,0.f};

    for (int nt = 0; nt < 16; ++nt) {
        float4 bb = *((const float4*)&b1s[nt*16 + quad*4]);
        f32x4 acc = {bb.x, bb.y, bb.z, bb.w};
        #pragma unroll
        for (int kc = 0; kc < 4; ++kc) {
            bf16x4 wf = *((const bf16x4*)&w1s[((nt*4 + kc)*64 + lane)*4]);
            acc = __builtin_amdgcn_mfma_f32_16x16x16bf16_1k(wf, xf[kc], acc, 0, 0, 0);
        }
        bf16x4 pf = pack4(fmaxf(acc[0], 0.f), fmaxf(acc[1], 0.f),
                          fmaxf(acc[2], 0.f), fmaxf(acc[3], 0.f));
        #pragma unroll
        for (int ct = 0; ct < 4; ++ct) {
            bf16x4 wf2 = *((const bf16x4*)&w2s[((nt*4 + ct)*64 + lane)*4]);
            oacc[ct] = __builtin_amdgcn_mfma_f32_16x16x16bf16_1k(wf2, pf, oacc[ct], 0, 0, 0);
        }
    }
    int r = r0 + wv*16 + l15;
    float s1 = 0.f, s2 = 0.f;
    if (r < TV) {
        #pragma unroll
        for (int ct = 0; ct < 4; ++ct) {
            #pragma unroll
            for (int j = 0; j < 4; ++j) {
                int c_out = ct*16 + quad*4 + j;
                size_t oi = (size_t)b*CTV + (size_t)c_out*TV + r;
                float val = oacc[ct][j] + b2s[c_out] + xb[(size_t)c_out*TV + r];
                out[oi] = val;
                s1 += val; s2 += val*val;
            }
        }
    }
    r1s[tid] = s1; r2s[tid] = s2;
    __syncthreads();
    for (int o = 128; o > 0; o >>= 1) {
        if (tid < o) { r1s[tid] += r1s[tid+o]; r2s[tid] += r2s[tid+o]; }
        __syncthreads();
    }
    if (tid == 0) { atomicAdd(&stats[b*2], r1s[0]); atomicAdd(&stats[b*2+1], r2s[0]); }
}

extern "C" void kernel_launch(void* const* d_in, const int* in_sizes, int n_in,
                              void* d_out, int out_size, void* d_ws, size_t ws_size,
                              hipStream_t stream) {
    const float* xin = (const float*)d_in[0];

    float* bufA  = (float*)d_ws;
    float* bufB  = bufA + S;
    float* stats = bufB + S;                        // 64 floats
    short* qb    = (short*)(stats + 64);            // [NBWH][NP][8]
    short* kb    = qb + (size_t)NBWH*NP*8;          // [NBWH][NP][16]
    short* vtb   = kb + (size_t)NBWH*NP*16;         // [NBWH][16][NP]
    short* att   = vtb + (size_t)NBWH*16*NP;        // [32][Nn][64] bf16

    prep_kernel<<<(NBWH*NP*8 + 255)/256, 256, 0, stream>>>(qb, kb, vtb, stats);

    for (int blk = 0; blk < 2; ++blk) {
        int o = 1 + blk*12;
        const float* qkvw = (const float*)d_in[o+0];
        const float* qkvb = (const float*)d_in[o+1];
        const float* pw   = (const float*)d_in[o+2];
        const float* pb   = (const float*)d_in[o+3];
        const float* fw1  = (const float*)d_in[o+4];
        const float* fb1  = (const float*)d_in[o+5];
        const float* fw2  = (const float*)d_in[o+6];
        const float* fb2  = (const float*)d_in[o+7];
        const float* g1   = (const float*)d_in[o+8];
        const float* be1  = (const float*)d_in[o+9];
        const float* g2   = (const float*)d_in[o+10];
        const float* be2  = (const float*)d_in[o+11];
        float* st1 = stats + blk*32;
        float* st2 = st1 + 16;

        const float* src = (blk == 0) ? xin : bufA;

        qkv_kernel<<<Bb*52, 256, 0, stream>>>(src, qkvw, qkvb, qb, kb, vtb);
        attn_kernel<<<NBWH, 1024, 0, stream>>>(qb, kb, vtb, att);
        proj_kernel<<<Bb*52, 256, 0, stream>>>(att, pw, pb, src, bufB, st1);
        ln_apply_kernel<<<S/256, 256, 0, stream>>>(bufB, g1, be1, st1, bufA, 0);
        ffn_kernel<<<Bb*52, 256, 0, stream>>>(bufA, fw1, fb1, fw2, fb2, bufB, st2);
        bool fin = (blk == 1);
        ln_apply_kernel<<<S/256, 256, 0, stream>>>(bufB, g2, be2, st2,
                                                   fin ? (float*)d_out : bufA,
                                                   WSZ/2);
    }
}

// Round 8
// 304.301 us; speedup vs baseline: 3.3626x; 1.0056x over previous
//
#include <hip/hip_runtime.h>
#include <hip/hip_bf16.h>

#define Bb  8
#define Cc  64
#define Tt  16
#define Vv  207
#define Hh  8
#define DH  8
#define NW  4
#define WSZ 4
#define Nn  (WSZ*Vv)       // 828
#define NP  832            // padded window length (52*16)
#define TV  (Tt*Vv)        // 3312
#define CTV (Cc*Tt*Vv)     // 211968
#define S   (Bb*CTV)       // 1695744
#define NBWH (Bb*NW*Hh)    // 256
#define EPSF 1e-5f
// log2(e)/sqrt(8): folded into Q so softmax uses exp2 directly
#define QSCALE 0.51006971401146f

typedef __attribute__((ext_vector_type(4))) short bf16x4;
typedef __attribute__((ext_vector_type(4))) float f32x4;
typedef __attribute__((ext_vector_type(2))) unsigned int u32x2;

static __device__ __forceinline__ short f2bf(float f) {
    union { float f; unsigned u; } v; v.f = f;
    unsigned r = (v.u + 0x7FFFu + ((v.u >> 16) & 1u)) >> 16;  // RNE
    return (short)r;
}

// cheap pack: round-half-up (bias cancels in softmax; fine elsewhere too)
static __device__ __forceinline__ bf16x4 pack4(float a, float b, float c, float d) {
    unsigned ua = __builtin_bit_cast(unsigned, a) + 0x8000u;
    unsigned ub = __builtin_bit_cast(unsigned, b) + 0x8000u;
    unsigned uc = __builtin_bit_cast(unsigned, c) + 0x8000u;
    unsigned ud = __builtin_bit_cast(unsigned, d) + 0x8000u;
    u32x2 t;
    t[0] = (ua >> 16) | (ub & 0xFFFF0000u);
    t[1] = (uc >> 16) | (ud & 0xFFFF0000u);
    return __builtin_bit_cast(bf16x4, t);
}

// ---------------- prep: zero stats, fill K/V pad regions ----------------
__global__ void prep_kernel(short* __restrict__ qb, short* __restrict__ kb,
                            short* __restrict__ vtb, float* __restrict__ stats) {
    int i = blockIdx.x*256 + threadIdx.x;
    if (i < 64) stats[i] = 0.f;
    if (i < NBWH*NP*8) {
        int bwh = i / (NP*8); int rest = i % (NP*8);
        int n = rest >> 3; int d = 8 + (rest & 7);
        kb[((size_t)bwh*NP + n)*16 + d] = 0;
        int d2 = 8 + rest / NP; int n2 = rest % NP;
        vtb[((size_t)bwh*16 + d2)*NP + n2] = (d2 == 8) ? (short)0x3F80 : (short)0;
    }
    if (i < NBWH*32) {
        int bwh = i >> 5; int rest = i & 31;
        int n = Nn + (rest >> 3); int d = rest & 7;
        qb[((size_t)bwh*NP + n)*8 + d] = 0;
        kb[((size_t)bwh*NP + n)*16 + d] = 0;
        int d3 = rest >> 2; int n3 = Nn + (rest & 3);
        vtb[((size_t)bwh*16 + d3)*NP + n3] = 0;
    }
}

// ---------------- QKV: MFMA GEMM + optional fused LN2(+roll) on input ----------------
// grid = 416 blocks, 256 threads; epilogue via LDS transpose, coalesced stores
__global__ __launch_bounds__(256) void qkv_kernel(const float* __restrict__ src,
        const float* __restrict__ st, const float* __restrict__ g, const float* __restrict__ be,
        const float* __restrict__ w, const float* __restrict__ bias,
        short* __restrict__ qb, short* __restrict__ kb, short* __restrict__ vtb) {
    __shared__ short wqs[3072*4];   // 24 KB weight frags
    __shared__ float bqs[192];
    __shared__ short os[64*196];    // 24.5 KB out transpose buffer [pos][ch], pad stride
    int tid = threadIdx.x;
    int b = blockIdx.x / 52;
    int r0 = (blockIdx.x % 52) * 64;
    const float* xb = src + (size_t)b*CTV;
    for (int s = tid; s < 3072; s += 256) {
        int nt = s >> 8; int kc = (s >> 6) & 3; int ln = s & 63;
        int li = ln & 15; int q = ln >> 4;
        bf16x4 f;
        #pragma unroll
        for (int j = 0; j < 4; ++j)
            f[j] = f2bf(w[(kc*16 + q*4 + j)*192 + nt*16 + li]);
        *((bf16x4*)&wqs[s*4]) = f;
    }
    if (tid < 192) bqs[tid] = bias[tid];
    __syncthreads();

    int lane = tid & 63; int wv = tid >> 6;
    int l15 = lane & 15; int quad = lane >> 4;
    int r = r0 + wv*16 + l15;
    int rc = (r < TV) ? r : TV-1;
    int t = rc / Vv; int vv = rc - t*Vv;
    float mean = 0.f, rstd = 0.f; int off;
    if (st) {
        mean = st[b*2] * (1.0f/CTV);
        float var = st[b*2+1] * (1.0f/CTV) - mean*mean;
        rstd = rsqrtf(var + EPSF);
        off = ((t+2)&15)*Vv + vv;       // roll(-2): read source at t+2
    } else off = rc;

    bf16x4 xf[4];
    #pragma unroll
    for (int kc = 0; kc < 4; ++kc) {
        #pragma unroll
        for (int j = 0; j < 4; ++j) {
            int idx = (kc*16 + quad*4 + j)*TV + off;
            float xv = xb[idx];
            if (st) xv = (xv - mean)*rstd*g[idx] + be[idx];
            xf[kc][j] = f2bf(xv);
        }
    }

    f32x4 accv[12];
    #pragma unroll
    for (int nt = 0; nt < 12; ++nt) {
        float4 bb = *((const float4*)&bqs[nt*16 + quad*4]);
        f32x4 acc = {bb.x, bb.y, bb.z, bb.w};
        #pragma unroll
        for (int kc = 0; kc < 4; ++kc) {
            bf16x4 wf = *((const bf16x4*)&wqs[((nt*4 + kc)*64 + lane)*4]);
            acc = __builtin_amdgcn_mfma_f32_16x16x16bf16_1k(wf, xf[kc], acc, 0, 0, 0);
        }
        accv[nt] = acc;
    }

    // transpose to LDS: os[pos*196 + ch], ch = nt*16 + quad*4 + j
    int pos = wv*16 + l15;
    #pragma unroll
    for (int nt = 0; nt < 12; ++nt) {
        f32x4 a = accv[nt];
        bf16x4 pk = (nt < 4) ? pack4(a[0]*QSCALE, a[1]*QSCALE, a[2]*QSCALE, a[3]*QSCALE)
                             : pack4(a[0], a[1], a[2], a[3]);
        *((bf16x4*)&os[pos*196 + nt*16 + quad*4]) = pk;
    }
    __syncthreads();

    // coalesced store phase: lanes consecutive in position
    int pp = tid & 63;
    int rr = r0 + pp;
    bool pv = rr < TV;
    int rrc = pv ? rr : TV-1;
    int t4 = rrc / Vv; int vv4 = rrc - t4*Vv;
    int n2 = (t4 & 3)*Vv + vv4;
    int wbase = (b*NW + (t4 >> 2))*Hh;
    #pragma unroll
    for (int i = 0; i < 2; ++i) {
        int h = i*4 + wv;
        if (pv) {
            bf16x4 q0 = *((const bf16x4*)&os[pp*196 + h*8]);
            bf16x4 q1 = *((const bf16x4*)&os[pp*196 + h*8 + 4]);
            short* qd = &qb[((size_t)(wbase + h)*NP + n2)*8];
            *((bf16x4*)qd) = q0; *((bf16x4*)(qd+4)) = q1;
            bf16x4 k0 = *((const bf16x4*)&os[pp*196 + 64 + h*8]);
            bf16x4 k1 = *((const bf16x4*)&os[pp*196 + 64 + h*8 + 4]);
            short* kd = &kb[((size_t)(wbase + h)*NP + n2)*16];
            *((bf16x4*)kd) = k0; *((bf16x4*)(kd+4)) = k1;
        }
    }
    #pragma unroll
    for (int i = 0; i < 16; ++i) {
        int hd = i*4 + wv;
        if (pv)
            vtb[((size_t)(wbase + (hd >> 3))*16 + (hd & 7))*NP + n2] = os[pp*196 + 128 + hd];
    }
}

// ---------------- Flash MFMA attention: 1024 threads/block, K/V in LDS ----------------
__global__ __launch_bounds__(1024) void attn_kernel(const short* __restrict__ qb,
        const short* __restrict__ kb, const short* __restrict__ vtb,
        short* __restrict__ att) {
    __shared__ short ks[NP*20];     // 33.3 KB
    __shared__ short vs[10*840];    // 16.8 KB
    int bwh = blockIdx.x;
    int tid = threadIdx.x;
    int lane = tid & 63;
    int wv = tid >> 6;              // 0..15
    int quad = lane >> 4;
    int l15 = lane & 15;

    const u32x2* kg = (const u32x2*)(kb + (size_t)bwh*NP*16);
    for (int idx = tid; idx < NP*4; idx += 1024) {
        int n = idx >> 2; int j = idx & 3;
        *((u32x2*)&ks[n*20 + j*4]) = kg[idx];
    }
    const u32x2* vg = (const u32x2*)(vtb + (size_t)bwh*16*NP);
    for (int idx = tid; idx < 9*208; idx += 1024) {
        int rr = idx / 208; int j = idx % 208;
        *((u32x2*)&vs[rr*840 + j*4]) = vg[rr*208 + j];
    }
    if (tid < 210) *((u32x2*)&vs[9*840 + tid*4]) = (u32x2){0u, 0u};
    __syncthreads();

    int nm = (wv < 4) ? 4 : 3;
    const short* qbase = qb + (size_t)bwh*NP*8;
    bf16x4 aq[4];
    f32x4 oacc[4];
    #pragma unroll
    for (int i = 0; i < 4; ++i) {
        aq[i] = (bf16x4){0,0,0,0};
        oacc[i] = (f32x4){0.f,0.f,0.f,0.f};
        if (i < nm && quad < 2)
            aq[i] = *(const bf16x4*)(qbase + (((wv + 16*i)*16 + l15)*8 + quad*4));
    }
    const short* kls = &ks[l15*20 + quad*4];
    const short* vls = &vs[((l15 < 9) ? l15 : 9)*840 + quad*4];

    for (int nt = 0; nt < 52; ++nt) {
        bf16x4 ak = *(const bf16x4*)(kls + nt*320);
        bf16x4 av = *(const bf16x4*)(vls + nt*16);
        bool mask = (nt == 51) && (quad == 3);   // pad keys n=828..831
        #pragma unroll
        for (int i = 0; i < 4; ++i) {
            if (i < nm) {
                f32x4 s = __builtin_amdgcn_mfma_f32_16x16x16bf16_1k(
                              ak, aq[i], (f32x4){0.f,0.f,0.f,0.f}, 0, 0, 0);
                bf16x4 pb = pack4(__builtin_amdgcn_exp2f(s[0]), __builtin_amdgcn_exp2f(s[1]),
                                  __builtin_amdgcn_exp2f(s[2]), __builtin_amdgcn_exp2f(s[3]));
                if (mask) pb = (bf16x4){0,0,0,0};
                oacc[i] = __builtin_amdgcn_mfma_f32_16x16x16bf16_1k(av, pb, oacc[i], 0, 0, 0);
            }
        }
    }
    int h = bwh & 7; int bw = bwh >> 3;
    #pragma unroll
    for (int i = 0; i < 4; ++i) {
        if (i < nm) {
            float ls = __shfl(oacc[i][0], 32 + l15, 64);   // l-sum = O row 8
            float inv = 1.f / ls;
            int m = (wv + 16*i)*16 + l15;
            if (quad < 2 && m < Nn) {
                bf16x4 ov = pack4(oacc[i][0]*inv, oacc[i][1]*inv,
                                  oacc[i][2]*inv, oacc[i][3]*inv);
                *((bf16x4*)&att[((size_t)bw*Nn + m)*Cc + h*DH + quad*4]) = ov;
            }
        }
    }
}

// ---------------- Proj: MFMA + residual (optional fused LN2+roll) + LN stats ----------------
__global__ __launch_bounds__(256) void proj_kernel(const short* __restrict__ att,
        const float* __restrict__ wo, const float* __restrict__ bo,
        const float* __restrict__ resid,
        const float* __restrict__ st, const float* __restrict__ g, const float* __restrict__ be,
        float* __restrict__ out, float* __restrict__ stats) {
    __shared__ short wos[1024*4];   // 8 KB
    __shared__ float bos[64];
    __shared__ float r1[256], r2[256];
    int tid = threadIdx.x;
    int b = blockIdx.x / 52;
    int r0 = (blockIdx.x % 52) * 64;
    const float* xb = resid + (size_t)b*CTV;
    for (int s = tid; s < 1024; s += 256) {
        int nt = s >> 8; int kc = (s >> 6) & 3; int ln = s & 63;
        int li = ln & 15; int q = ln >> 4;
        bf16x4 f;
        #pragma unroll
        for (int j = 0; j < 4; ++j)
            f[j] = f2bf(wo[(kc*16 + q*4 + j)*64 + nt*16 + li]);
        *((bf16x4*)&wos[s*4]) = f;
    }
    if (tid < 64) bos[tid] = bo[tid];
    __syncthreads();

    int lane = tid & 63; int wv = tid >> 6;
    int l15 = lane & 15; int quad = lane >> 4;
    int r = r0 + wv*16 + l15;
    bool valid = r < TV;
    int rc = valid ? r : TV-1;
    int t = rc / Vv; int vv = rc - t*Vv;
    int n = (t & 3)*Vv + vv;
    int bw = b*NW + (t >> 2);
    const short* arow = att + ((size_t)bw*Nn + n)*Cc;
    bf16x4 af[4];
    #pragma unroll
    for (int kc = 0; kc < 4; ++kc)
        af[kc] = *((const bf16x4*)&arow[kc*16 + quad*4]);

    f32x4 acc[4];
    #pragma unroll
    for (int nt = 0; nt < 4; ++nt) {
        float4 bb = *((const float4*)&bos[nt*16 + quad*4]);
        acc[nt] = (f32x4){bb.x, bb.y, bb.z, bb.w};
        #pragma unroll
        for (int kc = 0; kc < 4; ++kc) {
            bf16x4 wf = *((const bf16x4*)&wos[((nt*4 + kc)*64 + lane)*4]);
            acc[nt] = __builtin_amdgcn_mfma_f32_16x16x16bf16_1k(wf, af[kc], acc[nt], 0, 0, 0);
        }
    }
    float mean = 0.f, rstd = 0.f; int off;
    if (st) {
        mean = st[b*2] * (1.0f/CTV);
        float var = st[b*2+1] * (1.0f/CTV) - mean*mean;
        rstd = rsqrtf(var + EPSF);
        off = ((t+2)&15)*Vv + vv;
    } else off = rc;
    float s1 = 0.f, s2 = 0.f;
    if (valid) {
        #pragma unroll
        for (int nt = 0; nt < 4; ++nt) {
            #pragma unroll
            for (int j = 0; j < 4; ++j) {
                int c_out = nt*16 + quad*4 + j;
                int ridx = c_out*TV + off;
                float xv = xb[ridx];
                if (st) xv = (xv - mean)*rstd*g[ridx] + be[ridx];
                float val = acc[nt][j] + xv;
                out[(size_t)b*CTV + (size_t)c_out*TV + r] = val;
                s1 += val; s2 += val*val;
            }
        }
    }
    r1[tid] = s1; r2[tid] = s2;
    __syncthreads();
    for (int o = 128; o > 0; o >>= 1) {
        if (tid < o) { r1[tid] += r1[tid+o]; r2[tid] += r2[tid+o]; }
        __syncthreads();
    }
    if (tid == 0) { atomicAdd(&stats[b*2], r1[0]); atomicAdd(&stats[b*2+1], r2[0]); }
}

// ---------------- LayerNorm apply (+roll) — final output only ----------------
__global__ void ln_apply_kernel(const float* __restrict__ x,
                                const float* __restrict__ g,
                                const float* __restrict__ be,
                                const float* __restrict__ stats,
                                float* __restrict__ out,
                                int shift) {
    int idx = blockIdx.x*256 + threadIdx.x;
    if (idx >= S) return;
    int b = idx / CTV; int r = idx % CTV;
    int c = r / TV; int q2 = r % TV; int t = q2 / Vv; int vv = q2 % Vv;
    float mean = stats[b*2] * (1.0f/CTV);
    float var  = stats[b*2+1] * (1.0f/CTV) - mean*mean;
    float rstd = rsqrtf(var + EPSF);
    float val = (x[idx]-mean)*rstd*g[r] + be[r];
    int tout = (t - shift + Tt) % Tt;   // roll(-shift)
    size_t oidx = ((size_t)(b*Cc + c)*Tt + tout)*Vv + vv;
    out[oidx] = val;
}

// ---------------- FFN: fused LN1 on input, MFMA two-stage, residual, LN stats ----------------
// in-place safe: each element read only by the thread that writes it
__global__ __launch_bounds__(256) void ffn_kernel(const float* __restrict__ xin,
        const float* __restrict__ st, const float* __restrict__ g, const float* __restrict__ be,
        const float* __restrict__ w1, const float* __restrict__ b1,
        const float* __restrict__ w2, const float* __restrict__ b2,
        float* __restrict__ out, float* __restrict__ stats) {
    __shared__ short w1s[4096*4];
    __shared__ short w2s[4096*4];
    __shared__ short xsf[1024*4];
    __shared__ float b1s[256];
    __shared__ float b2s[64];
    __shared__ float r1s[256], r2s[256];
    int tid = threadIdx.x;
    int b = blockIdx.x / 52;
    int r0 = (blockIdx.x % 52) * 64;
    const float* xb = xin + (size_t)b*CTV;
    float mean = st[b*2] * (1.0f/CTV);
    float var  = st[b*2+1] * (1.0f/CTV) - mean*mean;
    float rstd = rsqrtf(var + EPSF);

    for (int s2 = tid; s2 < 4096; s2 += 256) {
        int nt = s2 >> 8; int kc = (s2 >> 6) & 3; int ln = s2 & 63;
        int l15 = ln & 15; int quad = ln >> 4;
        bf16x4 f;
        #pragma unroll
        for (int j = 0; j < 4; ++j)
            f[j] = f2bf(w1[(kc*16 + quad*4 + j)*256 + nt*16 + l15]);
        *((bf16x4*)&w1s[s2*4]) = f;
    }
    for (int s2 = tid; s2 < 4096; s2 += 256) {
        int nt = s2 >> 8; int ct = (s2 >> 6) & 3; int ln = s2 & 63;
        int l15 = ln & 15; int quad = ln >> 4;
        bf16x4 f;
        #pragma unroll
        for (int j = 0; j < 4; ++j)
            f[j] = f2bf(w2[(nt*16 + quad*4 + j)*64 + ct*16 + l15]);
        *((bf16x4*)&w2s[s2*4]) = f;
    }
    for (int s2 = tid; s2 < 1024; s2 += 256) {
        int wv2 = s2 >> 8; int kc = (s2 >> 6) & 3; int ln = s2 & 63;
        int l15 = ln & 15; int quad = ln >> 4;
        int r = r0 + wv2*16 + l15; if (r >= TV) r = TV-1;
        bf16x4 f;
        #pragma unroll
        for (int j = 0; j < 4; ++j) {
            int idx = (kc*16 + quad*4 + j)*TV + r;
            f[j] = f2bf((xb[idx] - mean)*rstd*g[idx] + be[idx]);
        }
        *((bf16x4*)&xsf[s2*4]) = f;
    }
    b1s[tid] = b1[tid];
    if (tid < 64) b2s[tid] = b2[tid];
    __syncthreads();

    int lane = tid & 63; int wv = tid >> 6;
    int l15 = lane & 15; int quad = lane >> 4;
    bf16x4 xf[4];
    #pragma unroll
    for (int kc = 0; kc < 4; ++kc)
        xf[kc] = *((const bf16x4*)&xsf[((wv*4 + kc)*64 + lane)*4]);

    f32x4 oacc[4];
    #pragma unroll
    for (int ct = 0; ct < 4; ++ct) oacc[ct] = (f32x4){0.f,0.f,0.f,0.f};

    for (int nt = 0; nt < 16; ++nt) {
        float4 bb = *((const float4*)&b1s[nt*16 + quad*4]);
        f32x4 acc = {bb.x, bb.y, bb.z, bb.w};
        #pragma unroll
        for (int kc = 0; kc < 4; ++kc) {
            bf16x4 wf = *((const bf16x4*)&w1s[((nt*4 + kc)*64 + lane)*4]);
            acc = __builtin_amdgcn_mfma_f32_16x16x16bf16_1k(wf, xf[kc], acc, 0, 0, 0);
        }
        bf16x4 pf = pack4(fmaxf(acc[0], 0.f), fmaxf(acc[1], 0.f),
                          fmaxf(acc[2], 0.f), fmaxf(acc[3], 0.f));
        #pragma unroll
        for (int ct = 0; ct < 4; ++ct) {
            bf16x4 wf2 = *((const bf16x4*)&w2s[((nt*4 + ct)*64 + lane)*4]);
            oacc[ct] = __builtin_amdgcn_mfma_f32_16x16x16bf16_1k(wf2, pf, oacc[ct], 0, 0, 0);
        }
    }
    int r = r0 + wv*16 + l15;
    float s1 = 0.f, s2 = 0.f;
    if (r < TV) {
        #pragma unroll
        for (int ct = 0; ct < 4; ++ct) {
            #pragma unroll
            for (int j = 0; j < 4; ++j) {
                int c_out = ct*16 + quad*4 + j;
                int idx = c_out*TV + r;
                float xv = (xb[idx] - mean)*rstd*g[idx] + be[idx];
                float val = oacc[ct][j] + b2s[c_out] + xv;
                out[(size_t)b*CTV + idx] = val;
                s1 += val; s2 += val*val;
            }
        }
    }
    r1s[tid] = s1; r2s[tid] = s2;
    __syncthreads();
    for (int o = 128; o > 0; o >>= 1) {
        if (tid < o) { r1s[tid] += r1s[tid+o]; r2s[tid] += r2s[tid+o]; }
        __syncthreads();
    }
    if (tid == 0) { atomicAdd(&stats[b*2], r1s[0]); atomicAdd(&stats[b*2+1], r2s[0]); }
}

extern "C" void kernel_launch(void* const* d_in, const int* in_sizes, int n_in,
                              void* d_out, int out_size, void* d_ws, size_t ws_size,
                              hipStream_t stream) {
    const float* xin = (const float*)d_in[0];

    float* bufA  = (float*)d_ws;
    float* bufB  = bufA + S;
    float* stats = bufB + S;                        // 64 floats
    short* qb    = (short*)(stats + 64);            // [NBWH][NP][8]
    short* kb    = qb + (size_t)NBWH*NP*8;          // [NBWH][NP][16]
    short* vtb   = kb + (size_t)NBWH*NP*16;         // [NBWH][16][NP]
    short* att   = vtb + (size_t)NBWH*16*NP;        // [32][Nn][64] bf16

    const float* A0  = (const float*)d_in[1+0*12];
    const float* A1  = (const float*)d_in[1+0*12+1];
    const float* A2  = (const float*)d_in[1+0*12+2];
    const float* A3  = (const float*)d_in[1+0*12+3];
    const float* A4  = (const float*)d_in[1+0*12+4];
    const float* A5  = (const float*)d_in[1+0*12+5];
    const float* A6  = (const float*)d_in[1+0*12+6];
    const float* A7  = (const float*)d_in[1+0*12+7];
    const float* A8  = (const float*)d_in[1+0*12+8];
    const float* A9  = (const float*)d_in[1+0*12+9];
    const float* A10 = (const float*)d_in[1+0*12+10];
    const float* A11 = (const float*)d_in[1+0*12+11];
    const float* B0  = (const float*)d_in[1+1*12];
    const float* B1  = (const float*)d_in[1+1*12+1];
    const float* B2  = (const float*)d_in[1+1*12+2];
    const float* B3  = (const float*)d_in[1+1*12+3];
    const float* B4  = (const float*)d_in[1+1*12+4];
    const float* B5  = (const float*)d_in[1+1*12+5];
    const float* B6  = (const float*)d_in[1+1*12+6];
    const float* B7  = (const float*)d_in[1+1*12+7];
    const float* B8  = (const float*)d_in[1+1*12+8];
    const float* B9  = (const float*)d_in[1+1*12+9];
    const float* B10 = (const float*)d_in[1+1*12+10];
    const float* B11 = (const float*)d_in[1+1*12+11];

    float* st1a = stats + 0;
    float* st2a = stats + 16;
    float* st1b = stats + 32;
    float* st2b = stats + 48;

    prep_kernel<<<(NBWH*NP*8 + 255)/256, 256, 0, stream>>>(qb, kb, vtb, stats);

    // ---- block A (input raw) ----
    qkv_kernel<<<Bb*52, 256, 0, stream>>>(xin, nullptr, nullptr, nullptr, A0, A1, qb, kb, vtb);
    attn_kernel<<<NBWH, 1024, 0, stream>>>(qb, kb, vtb, att);
    proj_kernel<<<Bb*52, 256, 0, stream>>>(att, A2, A3, xin, nullptr, nullptr, nullptr, bufB, st1a);
    ffn_kernel<<<Bb*52, 256, 0, stream>>>(bufB, st1a, A8, A9, A4, A5, A6, A7, bufB, st2a);
    // ---- block B (input = LN_a2(bufB) rolled, fused into consumers) ----
    qkv_kernel<<<Bb*52, 256, 0, stream>>>(bufB, st2a, A10, A11, B0, B1, qb, kb, vtb);
    attn_kernel<<<NBWH, 1024, 0, stream>>>(qb, kb, vtb, att);
    proj_kernel<<<Bb*52, 256, 0, stream>>>(att, B2, B3, bufB, st2a, A10, A11, bufA, st1b);
    ffn_kernel<<<Bb*52, 256, 0, stream>>>(bufA, st1b, B8, B9, B4, B5, B6, B7, bufA, st2b);
    // ---- final LN_b2 + roll -> d_out ----
    ln_apply_kernel<<<(S+255)/256, 256, 0, stream>>>(bufA, B10, B11, st2b, (float*)d_out, WSZ/2);
}

// Round 9
// 301.565 us; speedup vs baseline: 3.3931x; 1.0091x over previous
//
#include <hip/hip_runtime.h>
#include <hip/hip_bf16.h>

#define Bb  8
#define Cc  64
#define Tt  16
#define Vv  207
#define Hh  8
#define DH  8
#define NW  4
#define WSZ 4
#define Nn  (WSZ*Vv)       // 828
#define NP  832            // padded window length (52*16)
#define TV  (Tt*Vv)        // 3312
#define CTV (Cc*Tt*Vv)     // 211968
#define S   (Bb*CTV)       // 1695744
#define NBWH (Bb*NW*Hh)    // 256
#define EPSF 1e-5f
// log2(e)/sqrt(8): folded into Q so softmax uses exp2 directly
#define QSCALE 0.51006971401146f
// frag buffer sizes (in shorts)
#define FRAG_BWH (52*64*4)          // 13312 shorts per bwh
#define LAYER_WSZ 49152             // qkv 12288 + proj 4096 + w1 16384 + w2 16384

typedef __attribute__((ext_vector_type(4))) short bf16x4;
typedef __attribute__((ext_vector_type(4))) float f32x4;
typedef __attribute__((ext_vector_type(2))) unsigned int u32x2;

static __device__ __forceinline__ short f2bf(float f) {
    union { float f; unsigned u; } v; v.f = f;
    unsigned r = (v.u + 0x7FFFu + ((v.u >> 16) & 1u)) >> 16;  // RNE
    return (short)r;
}

// cheap pack: round-half-up (bias cancels in softmax; fine elsewhere too)
static __device__ __forceinline__ bf16x4 pack4(float a, float b, float c, float d) {
    unsigned ua = __builtin_bit_cast(unsigned, a) + 0x8000u;
    unsigned ub = __builtin_bit_cast(unsigned, b) + 0x8000u;
    unsigned uc = __builtin_bit_cast(unsigned, c) + 0x8000u;
    unsigned ud = __builtin_bit_cast(unsigned, d) + 0x8000u;
    u32x2 t;
    t[0] = (ua >> 16) | (ub & 0xFFFF0000u);
    t[1] = (uc >> 16) | (ud & 0xFFFF0000u);
    return __builtin_bit_cast(bf16x4, t);
}

// ---------------- prep_w: pre-convert all GEMM weights to bf16 frag order ----------------
// grid = 96 blocks x 256 (24576 frags across 2 layers); also zeroes stats
__global__ void prep_w_kernel(const float* __restrict__ qa, const float* __restrict__ pa,
                              const float* __restrict__ w1a, const float* __restrict__ w2a,
                              const float* __restrict__ qbw, const float* __restrict__ pbw,
                              const float* __restrict__ w1b, const float* __restrict__ w2b,
                              short* __restrict__ wf, float* __restrict__ stats) {
    if (blockIdx.x == 0 && threadIdx.x < 64) stats[threadIdx.x] = 0.f;
    int i = blockIdx.x*256 + threadIdx.x;
    int l = i / 12288; int f = i % 12288;
    const float* qw = l ? qbw : qa;
    const float* pw = l ? pbw : pa;
    const float* w1 = l ? w1b : w1a;
    const float* w2 = l ? w2b : w2a;
    short* dst = wf + l*LAYER_WSZ;
    bf16x4 out;
    if (f < 3072) {
        int s = f; int nt = s>>8; int kc = (s>>6)&3; int ln = s&63;
        int li = ln&15; int q = ln>>4;
        #pragma unroll
        for (int j = 0; j < 4; ++j) out[j] = f2bf(qw[(kc*16+q*4+j)*192 + nt*16+li]);
        *((bf16x4*)&dst[s*4]) = out;
    } else if (f < 4096) {
        int s = f-3072; int nt = s>>8; int kc = (s>>6)&3; int ln = s&63;
        int li = ln&15; int q = ln>>4;
        #pragma unroll
        for (int j = 0; j < 4; ++j) out[j] = f2bf(pw[(kc*16+q*4+j)*64 + nt*16+li]);
        *((bf16x4*)&dst[12288 + s*4]) = out;
    } else if (f < 8192) {
        int s = f-4096; int nt = s>>8; int kc = (s>>6)&3; int ln = s&63;
        int li = ln&15; int q = ln>>4;
        #pragma unroll
        for (int j = 0; j < 4; ++j) out[j] = f2bf(w1[(kc*16+q*4+j)*256 + nt*16+li]);
        *((bf16x4*)&dst[16384 + s*4]) = out;
    } else {
        int s = f-8192; int nt = s>>8; int ct = (s>>6)&3; int ln = s&63;
        int li = ln&15; int q = ln>>4;
        #pragma unroll
        for (int j = 0; j < 4; ++j) out[j] = f2bf(w2[(nt*16+q*4+j)*64 + ct*16+li]);
        *((bf16x4*)&dst[32768 + s*4]) = out;
    }
}

// ---------------- prep_pads: init constant regions of q/k/v frag buffers ----------------
// qf/kf: lanes 32..63 (quads 2,3) zero.  vf: lanes with l15==8 -> 1.0, l15>8 -> 0.
// grid = 1664 blocks x 256 (NBWH*52*32 items)
__global__ void prep_pads_kernel(short* __restrict__ qf, short* __restrict__ kf,
                                 short* __restrict__ vf) {
    int i = blockIdx.x*256 + threadIdx.x;
    int bwh = i / 1664; int rest = i % 1664;
    int nt = rest >> 5; int u = rest & 31;
    size_t base = (size_t)bwh*FRAG_BWH + nt*256;
    *((u32x2*)&qf[base + (32+u)*4]) = (u32x2){0u,0u};
    *((u32x2*)&kf[base + (32+u)*4]) = (u32x2){0u,0u};
    int vlane = (u>>3)*16 + 8 + (u&7);
    short v = ((u&7) == 0) ? (short)0x3F80 : (short)0;
    bf16x4 vv4 = {v,v,v,v};
    *((bf16x4*)&vf[base + vlane*4]) = vv4;
}

// ---------------- QKV: MFMA GEMM + optional fused LN2(+roll); frag-ordered outputs ----------------
// grid = 416 blocks, 256 threads
__global__ __launch_bounds__(256) void qkv_kernel(const float* __restrict__ src,
        const float* __restrict__ st, const float* __restrict__ g, const float* __restrict__ be,
        const short* __restrict__ wfq, const float* __restrict__ bias,
        short* __restrict__ qf, short* __restrict__ kf, short* __restrict__ vf) {
    __shared__ short wqs[12288];    // 24 KB weight frags
    __shared__ float bqs[192];
    __shared__ short os[64*196];    // 24.5 KB transpose buffer [pos][ch]
    int tid = threadIdx.x;
    int b = blockIdx.x / 52;
    int r0 = (blockIdx.x % 52) * 64;
    const float* xb = src + (size_t)b*CTV;
    {
        const u32x2* wsrc = (const u32x2*)wfq;
        u32x2* wdst = (u32x2*)wqs;
        for (int s = tid; s < 3072; s += 256) wdst[s] = wsrc[s];
    }
    if (tid < 192) bqs[tid] = bias[tid];
    __syncthreads();

    int lane = tid & 63; int wv = tid >> 6;
    int l15 = lane & 15; int quad = lane >> 4;
    int r = r0 + wv*16 + l15;
    int rc = (r < TV) ? r : TV-1;
    int t = rc / Vv; int vv = rc - t*Vv;
    float mean = 0.f, rstd = 0.f; int off;
    if (st) {
        mean = st[b*2] * (1.0f/CTV);
        float var = st[b*2+1] * (1.0f/CTV) - mean*mean;
        rstd = rsqrtf(var + EPSF);
        off = ((t+2)&15)*Vv + vv;       // roll(-2): read source at t+2
    } else off = rc;

    bf16x4 xf[4];
    #pragma unroll
    for (int kc = 0; kc < 4; ++kc) {
        #pragma unroll
        for (int j = 0; j < 4; ++j) {
            int idx = (kc*16 + quad*4 + j)*TV + off;
            float xv = xb[idx];
            if (st) xv = (xv - mean)*rstd*g[idx] + be[idx];
            xf[kc][j] = f2bf(xv);
        }
    }

    f32x4 accv[12];
    #pragma unroll
    for (int nt = 0; nt < 12; ++nt) {
        float4 bb = *((const float4*)&bqs[nt*16 + quad*4]);
        f32x4 acc = {bb.x, bb.y, bb.z, bb.w};
        #pragma unroll
        for (int kc = 0; kc < 4; ++kc) {
            bf16x4 wf2 = *((const bf16x4*)&wqs[((nt*4 + kc)*64 + lane)*4]);
            acc = __builtin_amdgcn_mfma_f32_16x16x16bf16_1k(wf2, xf[kc], acc, 0, 0, 0);
        }
        accv[nt] = acc;
    }

    // transpose to LDS: os[pos*196 + ch], ch = nt*16 + quad*4 + j
    int pos = wv*16 + l15;
    #pragma unroll
    for (int nt = 0; nt < 12; ++nt) {
        f32x4 a = accv[nt];
        bf16x4 pk = (nt < 4) ? pack4(a[0]*QSCALE, a[1]*QSCALE, a[2]*QSCALE, a[3]*QSCALE)
                             : pack4(a[0], a[1], a[2], a[3]);
        *((bf16x4*)&os[pos*196 + nt*16 + quad*4]) = pk;
    }
    __syncthreads();

    // store phase: frag-ordered outputs, coalesced 8B stores for q/k
    int pp = tid & 63;
    int rr = r0 + pp;
    bool pv = rr < TV;
    int rrc = pv ? rr : TV-1;
    int t4 = rrc / Vv; int vv4 = rrc - t4*Vv;
    int n2 = (t4 & 3)*Vv + vv4;
    int nt2 = n2 >> 4; int l15n = n2 & 15;
    int quadn = (n2 & 15) >> 2; int jn = n2 & 3;
    int wbase = (b*NW + (t4 >> 2))*Hh;
    if (pv) {
        #pragma unroll
        for (int i = 0; i < 2; ++i) {
            int h = i*4 + wv;
            size_t fb = ((size_t)(wbase+h)*52 + nt2)*256;
            bf16x4 q0 = *((const bf16x4*)&os[pp*196 + h*8]);
            bf16x4 q1 = *((const bf16x4*)&os[pp*196 + h*8 + 4]);
            *((bf16x4*)&qf[fb + l15n*4])        = q0;
            *((bf16x4*)&qf[fb + (16 + l15n)*4]) = q1;
            bf16x4 k0 = *((const bf16x4*)&os[pp*196 + 64 + h*8]);
            bf16x4 k1 = *((const bf16x4*)&os[pp*196 + 64 + h*8 + 4]);
            *((bf16x4*)&kf[fb + l15n*4])        = k0;
            *((bf16x4*)&kf[fb + (16 + l15n)*4]) = k1;
        }
        #pragma unroll
        for (int i = 0; i < 16; ++i) {
            int hd = i*4 + wv;
            int h = hd >> 3; int d = hd & 7;
            vf[(((size_t)(wbase+h)*52 + nt2)*64 + quadn*16 + d)*4 + jn]
                = os[pp*196 + 128 + hd];
        }
    }
}

// ---------------- Flash MFMA attention: frag-resident K/V in LDS, conflict-free ----------------
// grid = 256 blocks, 1024 threads (16 waves; wave wv owns m-tiles wv+16*i)
__global__ __launch_bounds__(1024) void attn_kernel(const short* __restrict__ qf,
        const short* __restrict__ kf, const short* __restrict__ vf,
        short* __restrict__ att) {
    __shared__ short ks2[FRAG_BWH];   // 26.6 KB
    __shared__ short vs2[FRAG_BWH];   // 26.6 KB
    int bwh = blockIdx.x;
    int tid = threadIdx.x;
    int lane = tid & 63;
    int wv = tid >> 6;
    int quad = lane >> 4;
    int l15 = lane & 15;

    {
        const u32x2* kg = (const u32x2*)(kf + (size_t)bwh*FRAG_BWH);
        const u32x2* vg = (const u32x2*)(vf + (size_t)bwh*FRAG_BWH);
        u32x2* kd = (u32x2*)ks2; u32x2* vd = (u32x2*)vs2;
        for (int idx = tid; idx < 3328; idx += 1024) { kd[idx] = kg[idx]; vd[idx] = vg[idx]; }
    }
    __syncthreads();

    int nm = (wv < 4) ? 4 : 3;
    const short* qbase = qf + (size_t)bwh*FRAG_BWH;
    bf16x4 aq[4];
    f32x4 oacc[4];
    #pragma unroll
    for (int i = 0; i < 4; ++i) {
        aq[i] = (bf16x4){0,0,0,0};
        oacc[i] = (f32x4){0.f,0.f,0.f,0.f};
        if (i < nm)
            aq[i] = *(const bf16x4*)(qbase + ((wv + 16*i)*256 + lane*4));
    }

    for (int nt = 0; nt < 52; ++nt) {
        bf16x4 ak = *(const bf16x4*)&ks2[nt*256 + lane*4];
        bf16x4 av = *(const bf16x4*)&vs2[nt*256 + lane*4];
        bool mask = (nt == 51) && (quad == 3);   // pad keys n=828..831
        #pragma unroll
        for (int i = 0; i < 4; ++i) {
            if (i < nm) {
                f32x4 s = __builtin_amdgcn_mfma_f32_16x16x16bf16_1k(
                              ak, aq[i], (f32x4){0.f,0.f,0.f,0.f}, 0, 0, 0);
                bf16x4 pb = pack4(__builtin_amdgcn_exp2f(s[0]), __builtin_amdgcn_exp2f(s[1]),
                                  __builtin_amdgcn_exp2f(s[2]), __builtin_amdgcn_exp2f(s[3]));
                if (mask) pb = (bf16x4){0,0,0,0};
                oacc[i] = __builtin_amdgcn_mfma_f32_16x16x16bf16_1k(av, pb, oacc[i], 0, 0, 0);
            }
        }
    }
    int h = bwh & 7; int bw = bwh >> 3;
    #pragma unroll
    for (int i = 0; i < 4; ++i) {
        if (i < nm) {
            float ls = __shfl(oacc[i][0], 32 + l15, 64);   // l-sum = O row 8
            float inv = 1.f / ls;
            int m = (wv + 16*i)*16 + l15;
            if (quad < 2 && m < Nn) {
                bf16x4 ov = pack4(oacc[i][0]*inv, oacc[i][1]*inv,
                                  oacc[i][2]*inv, oacc[i][3]*inv);
                *((bf16x4*)&att[((size_t)bw*Nn + m)*Cc + h*DH + quad*4]) = ov;
            }
        }
    }
}

// ---------------- Proj: MFMA + residual (optional fused LN2+roll) + LN stats ----------------
__global__ __launch_bounds__(256) void proj_kernel(const short* __restrict__ att,
        const short* __restrict__ wfp, const float* __restrict__ bo,
        const float* __restrict__ resid,
        const float* __restrict__ st, const float* __restrict__ g, const float* __restrict__ be,
        float* __restrict__ out, float* __restrict__ stats) {
    __shared__ short wos[4096];     // 8 KB
    __shared__ float bos[64];
    __shared__ float r1[256], r2[256];
    int tid = threadIdx.x;
    int b = blockIdx.x / 52;
    int r0 = (blockIdx.x % 52) * 64;
    const float* xb = resid + (size_t)b*CTV;
    {
        const u32x2* wsrc = (const u32x2*)wfp;
        u32x2* wdst = (u32x2*)wos;
        for (int s = tid; s < 1024; s += 256) wdst[s] = wsrc[s];
    }
    if (tid < 64) bos[tid] = bo[tid];
    __syncthreads();

    int lane = tid & 63; int wv = tid >> 6;
    int l15 = lane & 15; int quad = lane >> 4;
    int r = r0 + wv*16 + l15;
    bool valid = r < TV;
    int rc = valid ? r : TV-1;
    int t = rc / Vv; int vv = rc - t*Vv;
    int n = (t & 3)*Vv + vv;
    int bw = b*NW + (t >> 2);
    const short* arow = att + ((size_t)bw*Nn + n)*Cc;
    bf16x4 af[4];
    #pragma unroll
    for (int kc = 0; kc < 4; ++kc)
        af[kc] = *((const bf16x4*)&arow[kc*16 + quad*4]);

    f32x4 acc[4];
    #pragma unroll
    for (int nt = 0; nt < 4; ++nt) {
        float4 bb = *((const float4*)&bos[nt*16 + quad*4]);
        acc[nt] = (f32x4){bb.x, bb.y, bb.z, bb.w};
        #pragma unroll
        for (int kc = 0; kc < 4; ++kc) {
            bf16x4 wf2 = *((const bf16x4*)&wos[((nt*4 + kc)*64 + lane)*4]);
            acc[nt] = __builtin_amdgcn_mfma_f32_16x16x16bf16_1k(wf2, af[kc], acc[nt], 0, 0, 0);
        }
    }
    float mean = 0.f, rstd = 0.f; int off;
    if (st) {
        mean = st[b*2] * (1.0f/CTV);
        float var = st[b*2+1] * (1.0f/CTV) - mean*mean;
        rstd = rsqrtf(var + EPSF);
        off = ((t+2)&15)*Vv + vv;
    } else off = rc;
    float s1 = 0.f, s2 = 0.f;
    if (valid) {
        #pragma unroll
        for (int nt = 0; nt < 4; ++nt) {
            #pragma unroll
            for (int j = 0; j < 4; ++j) {
                int c_out = nt*16 + quad*4 + j;
                int ridx = c_out*TV + off;
                float xv = xb[ridx];
                if (st) xv = (xv - mean)*rstd*g[ridx] + be[ridx];
                float val = acc[nt][j] + xv;
                out[(size_t)b*CTV + (size_t)c_out*TV + r] = val;
                s1 += val; s2 += val*val;
            }
        }
    }
    r1[tid] = s1; r2[tid] = s2;
    __syncthreads();
    for (int o = 128; o > 0; o >>= 1) {
        if (tid < o) { r1[tid] += r1[tid+o]; r2[tid] += r2[tid+o]; }
        __syncthreads();
    }
    if (tid == 0) { atomicAdd(&stats[b*2], r1[0]); atomicAdd(&stats[b*2+1], r2[0]); }
}

// ---------------- LayerNorm apply (+roll) — final output only ----------------
__global__ void ln_apply_kernel(const float* __restrict__ x,
                                const float* __restrict__ g,
                                const float* __restrict__ be,
                                const float* __restrict__ stats,
                                float* __restrict__ out,
                                int shift) {
    int idx = blockIdx.x*256 + threadIdx.x;
    if (idx >= S) return;
    int b = idx / CTV; int r = idx % CTV;
    int c = r / TV; int q2 = r % TV; int t = q2 / Vv; int vv = q2 % Vv;
    float mean = stats[b*2] * (1.0f/CTV);
    float var  = stats[b*2+1] * (1.0f/CTV) - mean*mean;
    float rstd = rsqrtf(var + EPSF);
    float val = (x[idx]-mean)*rstd*g[r] + be[r];
    int tout = (t - shift + Tt) % Tt;   // roll(-shift)
    size_t oidx = ((size_t)(b*Cc + c)*Tt + tout)*Vv + vv;
    out[oidx] = val;
}

// ---------------- FFN: fused LN1 on input, MFMA two-stage, residual, LN stats ----------------
__global__ __launch_bounds__(256) void ffn_kernel(const float* __restrict__ xin,
        const float* __restrict__ st, const float* __restrict__ g, const float* __restrict__ be,
        const short* __restrict__ wf1, const float* __restrict__ b1,
        const short* __restrict__ wf2g, const float* __restrict__ b2,
        float* __restrict__ out, float* __restrict__ stats) {
    __shared__ short w1s[16384];    // 32 KB
    __shared__ short w2s[16384];    // 32 KB
    __shared__ short xsf[4096];     // 8 KB
    __shared__ float b1s[256];
    __shared__ float b2s[64];
    __shared__ float r1s[256], r2s[256];
    int tid = threadIdx.x;
    int b = blockIdx.x / 52;
    int r0 = (blockIdx.x % 52) * 64;
    const float* xb = xin + (size_t)b*CTV;
    float mean = st[b*2] * (1.0f/CTV);
    float var  = st[b*2+1] * (1.0f/CTV) - mean*mean;
    float rstd = rsqrtf(var + EPSF);

    {
        const u32x2* s1p = (const u32x2*)wf1;
        const u32x2* s2p = (const u32x2*)wf2g;
        u32x2* d1 = (u32x2*)w1s; u32x2* d2 = (u32x2*)w2s;
        for (int s = tid; s < 4096; s += 256) { d1[s] = s1p[s]; d2[s] = s2p[s]; }
    }
    for (int s2 = tid; s2 < 1024; s2 += 256) {
        int wv2 = s2 >> 8; int kc = (s2 >> 6) & 3; int ln = s2 & 63;
        int l15 = ln & 15; int quad = ln >> 4;
        int r = r0 + wv2*16 + l15; if (r >= TV) r = TV-1;
        bf16x4 f;
        #pragma unroll
        for (int j = 0; j < 4; ++j) {
            int idx = (kc*16 + quad*4 + j)*TV + r;
            f[j] = f2bf((xb[idx] - mean)*rstd*g[idx] + be[idx]);
        }
        *((bf16x4*)&xsf[s2*4]) = f;
    }
    b1s[tid] = b1[tid];
    if (tid < 64) b2s[tid] = b2[tid];
    __syncthreads();

    int lane = tid & 63; int wv = tid >> 6;
    int l15 = lane & 15; int quad = lane >> 4;
    bf16x4 xf[4];
    #pragma unroll
    for (int kc = 0; kc < 4; ++kc)
        xf[kc] = *((const bf16x4*)&xsf[((wv*4 + kc)*64 + lane)*4]);

    f32x4 oacc[4];
    #pragma unroll
    for (int ct = 0; ct < 4; ++ct) oacc[ct] = (f32x4){0.f,0.f,0.f,0.f};

    for (int nt = 0; nt < 16; ++nt) {
        float4 bb = *((const float4*)&b1s[nt*16 + quad*4]);
        f32x4 acc = {bb.x, bb.y, bb.z, bb.w};
        #pragma unroll
        for (int kc = 0; kc < 4; ++kc) {
            bf16x4 wfv = *((const bf16x4*)&w1s[((nt*4 + kc)*64 + lane)*4]);
            acc = __builtin_amdgcn_mfma_f32_16x16x16bf16_1k(wfv, xf[kc], acc, 0, 0, 0);
        }
        bf16x4 pf = pack4(fmaxf(acc[0], 0.f), fmaxf(acc[1], 0.f),
                          fmaxf(acc[2], 0.f), fmaxf(acc[3], 0.f));
        #pragma unroll
        for (int ct = 0; ct < 4; ++ct) {
            bf16x4 wfv2 = *((const bf16x4*)&w2s[((nt*4 + ct)*64 + lane)*4]);
            oacc[ct] = __builtin_amdgcn_mfma_f32_16x16x16bf16_1k(wfv2, pf, oacc[ct], 0, 0, 0);
        }
    }
    int r = r0 + wv*16 + l15;
    float s1 = 0.f, s2 = 0.f;
    if (r < TV) {
        #pragma unroll
        for (int ct = 0; ct < 4; ++ct) {
            #pragma unroll
            for (int j = 0; j < 4; ++j) {
                int c_out = ct*16 + quad*4 + j;
                int idx = c_out*TV + r;
                float xv = (xb[idx] - mean)*rstd*g[idx] + be[idx];
                float val = oacc[ct][j] + b2s[c_out] + xv;
                out[(size_t)b*CTV + idx] = val;
                s1 += val; s2 += val*val;
            }
        }
    }
    r1s[tid] = s1; r2s[tid] = s2;
    __syncthreads();
    for (int o = 128; o > 0; o >>= 1) {
        if (tid < o) { r1s[tid] += r1s[tid+o]; r2s[tid] += r2s[tid+o]; }
        __syncthreads();
    }
    if (tid == 0) { atomicAdd(&stats[b*2], r1s[0]); atomicAdd(&stats[b*2+1], r2s[0]); }
}

extern "C" void kernel_launch(void* const* d_in, const int* in_sizes, int n_in,
                              void* d_out, int out_size, void* d_ws, size_t ws_size,
                              hipStream_t stream) {
    const float* xin = (const float*)d_in[0];

    float* bufA  = (float*)d_ws;
    float* bufB  = bufA + S;
    float* stats = bufB + S;                        // 64 floats
    short* qf    = (short*)(stats + 64);            // [NBWH][52][64][4]
    short* kf    = qf + (size_t)NBWH*FRAG_BWH;
    short* vf    = kf + (size_t)NBWH*FRAG_BWH;
    short* att   = vf + (size_t)NBWH*FRAG_BWH;      // [32][Nn][64] bf16
    short* wf    = att + (size_t)32*Nn*64;          // weight frags, 2 layers

    const float* A0  = (const float*)d_in[1];
    const float* A1  = (const float*)d_in[2];
    const float* A2  = (const float*)d_in[3];
    const float* A3  = (const float*)d_in[4];
    const float* A4  = (const float*)d_in[5];
    const float* A5  = (const float*)d_in[6];
    const float* A6  = (const float*)d_in[7];
    const float* A7  = (const float*)d_in[8];
    const float* A8  = (const float*)d_in[9];
    const float* A9  = (const float*)d_in[10];
    const float* A10 = (const float*)d_in[11];
    const float* A11 = (const float*)d_in[12];
    const float* B0  = (const float*)d_in[13];
    const float* B1  = (const float*)d_in[14];
    const float* B2  = (const float*)d_in[15];
    const float* B3  = (const float*)d_in[16];
    const float* B4  = (const float*)d_in[17];
    const float* B5  = (const float*)d_in[18];
    const float* B6  = (const float*)d_in[19];
    const float* B7  = (const float*)d_in[20];
    const float* B8  = (const float*)d_in[21];
    const float* B9  = (const float*)d_in[22];
    const float* B10 = (const float*)d_in[23];
    const float* B11 = (const float*)d_in[24];

    float* st1a = stats + 0;
    float* st2a = stats + 16;
    float* st1b = stats + 32;
    float* st2b = stats + 48;

    short* wfA = wf;
    short* wfB = wf + LAYER_WSZ;

    prep_w_kernel<<<96, 256, 0, stream>>>(A0, A2, A4, A6, B0, B2, B4, B6, wf, stats);
    prep_pads_kernel<<<1664, 256, 0, stream>>>(qf, kf, vf);

    // ---- block A (input raw) ----
    qkv_kernel<<<Bb*52, 256, 0, stream>>>(xin, nullptr, nullptr, nullptr,
                                          wfA, A1, qf, kf, vf);
    attn_kernel<<<NBWH, 1024, 0, stream>>>(qf, kf, vf, att);
    proj_kernel<<<Bb*52, 256, 0, stream>>>(att, wfA + 12288, A3, xin,
                                           nullptr, nullptr, nullptr, bufB, st1a);
    ffn_kernel<<<Bb*52, 256, 0, stream>>>(bufB, st1a, A8, A9,
                                          wfA + 16384, A5, wfA + 32768, A7, bufB, st2a);
    // ---- block B (input = LN_a2(bufB) rolled, fused into consumers) ----
    qkv_kernel<<<Bb*52, 256, 0, stream>>>(bufB, st2a, A10, A11,
                                          wfB, B1, qf, kf, vf);
    attn_kernel<<<NBWH, 1024, 0, stream>>>(qf, kf, vf, att);
    proj_kernel<<<Bb*52, 256, 0, stream>>>(att, wfB + 12288, B3, bufB,
                                           st2a, A10, A11, bufA, st1b);
    ffn_kernel<<<Bb*52, 256, 0, stream>>>(bufA, st1b, B8, B9,
                                          wfB + 16384, B5, wfB + 32768, B7, bufA, st2b);
    // ---- final LN_b2 + roll -> d_out ----
    ln_apply_kernel<<<(S+255)/256, 256, 0, stream>>>(bufA, B10, B11, st2b, (float*)d_out, WSZ/2);
}